// Round 1
// baseline (3391.429 us; speedup 1.0000x reference)
//
#include <hip/hip_runtime.h>

#define N_PTS 16384
#define NBATCH 32
#define TILE 32
#define NBLK (N_PTS / TILE) /* 512 */

__device__ __forceinline__ float gelu_exact(float x) {
    return 0.5f * x * (1.0f + erff(x * 0.70710678118654752440f));
}
__device__ __forceinline__ unsigned fkey(float x) {
    unsigned u = __float_as_uint(x);
    return (u & 0x80000000u) ? ~u : (u | 0x80000000u);
}
__device__ __forceinline__ float funkey(unsigned k) {
    return (k & 0x80000000u) ? __uint_as_float(k ^ 0x80000000u) : __uint_as_float(~k);
}

// ---------------- register-blocked tile GEMM: 32 points x DOUT outputs -------
// A: transposed activations [ch][36] (pad keeps b128 16B-aligned, banks spread)
// thread: og = tid>>3 (32 groups of OO outputs), pg = tid&7 (8 groups of 4 pts)
template<int DIN, int OO>
__device__ __forceinline__ void gemm_acc(const float (*A)[36], const float* __restrict__ W,
                                         int og, int pg, float acc[4][OO]) {
#pragma unroll
    for (int q = 0; q < 4; ++q)
#pragma unroll
        for (int j = 0; j < OO; ++j) acc[q][j] = 0.f;
#pragma unroll 2
    for (int i = 0; i < DIN; i += 4) {
        float a[4][4];
#pragma unroll
        for (int u = 0; u < 4; ++u) {
            float4 t = *(const float4*)&A[i + u][pg * 4];
            a[u][0] = t.x; a[u][1] = t.y; a[u][2] = t.z; a[u][3] = t.w;
        }
#pragma unroll
        for (int j = 0; j < OO; ++j) {
            float4 w = *(const float4*)&W[(size_t)(og * OO + j) * DIN + i];
#pragma unroll
            for (int q = 0; q < 4; ++q)
                acc[q][j] += a[0][q] * w.x + a[1][q] * w.y + a[2][q] * w.z + a[3][q] * w.w;
        }
    }
}

template<int OO>
__device__ __forceinline__ void store_B(float (*Bb)[264], const float* __restrict__ bias,
                                        int og, int pg, float acc[4][OO]) {
#pragma unroll
    for (int j = 0; j < OO; ++j) {
        float bv = bias[og * OO + j];
#pragma unroll
        for (int q = 0; q < 4; ++q) Bb[pg * 4 + q][og * OO + j] = acc[q][j] + bv;
    }
}

// LN over channels of one point; 8 lanes per point (consecutive lanes)
template<int DOUT, bool DOGELU>
__device__ __forceinline__ void layer_ln(float (*A)[36], const float (*Bb)[264],
                                         const float* __restrict__ g, const float* __restrict__ be,
                                         int tid) {
    constexpr int CH = DOUT / 8;
    const int p = tid >> 3, s = tid & 7;
    float v[CH];
    float sum = 0.f, ss = 0.f;
#pragma unroll
    for (int k = 0; k < CH; k += 4) {
        float4 t = *(const float4*)&Bb[p][s * CH + k];
        v[k] = t.x; v[k + 1] = t.y; v[k + 2] = t.z; v[k + 3] = t.w;
        sum += t.x + t.y + t.z + t.w;
        ss += t.x * t.x + t.y * t.y + t.z * t.z + t.w * t.w;
    }
    sum += __shfl_xor(sum, 1); ss += __shfl_xor(ss, 1);
    sum += __shfl_xor(sum, 2); ss += __shfl_xor(ss, 2);
    sum += __shfl_xor(sum, 4); ss += __shfl_xor(ss, 4);
    const float mean = sum * (1.f / DOUT);
    const float var = ss * (1.f / DOUT) - mean * mean;
    const float rstd = rsqrtf(var + 1e-5f);
#pragma unroll
    for (int k = 0; k < CH; ++k) {
        int c = s * CH + k;
        float x = (v[k] - mean) * rstd * g[c] + be[c];
        if (DOGELU) x = gelu_exact(x);
        A[c][p] = x;
    }
}

// ---------------- kernel 0: init atomic-max keys ----------------------------
__global__ void init_kernel(unsigned* __restrict__ maxkey) {
    maxkey[blockIdx.x * 256 + threadIdx.x] = 0u;
}

// ---------------- kernel 1: PointNet encoder --------------------------------
__global__ __launch_bounds__(256)
void pointnet_kernel(const float* __restrict__ points,
                     const float* __restrict__ W1, const float* __restrict__ B1,
                     const float* __restrict__ G1, const float* __restrict__ E1,
                     const float* __restrict__ W2, const float* __restrict__ B2,
                     const float* __restrict__ G2, const float* __restrict__ E2,
                     const float* __restrict__ W3, const float* __restrict__ B3,
                     const float* __restrict__ G3, const float* __restrict__ E3,
                     const float* __restrict__ W4, const float* __restrict__ B4,
                     const float* __restrict__ G4, const float* __restrict__ E4,
                     unsigned* __restrict__ maxkey) {
    __shared__ float A[256][36];
    __shared__ float Bb[TILE][264];
    const int b = blockIdx.x / NBLK;
    const int n0 = (blockIdx.x % NBLK) * TILE;
    const int tid = threadIdx.x;
    const int og = tid >> 3, pg = tid & 7;

    for (int q = tid; q < TILE * 3; q += 256) {
        int p = q / 3, d = q - p * 3;
        A[d][p] = points[((size_t)(b * N_PTS) + n0 + p) * 3 + d];
    }
    __syncthreads();
    { // layer1: 3 -> 128
        float a[3][4];
#pragma unroll
        for (int u = 0; u < 3; ++u) {
            float4 t = *(const float4*)&A[u][pg * 4];
            a[u][0] = t.x; a[u][1] = t.y; a[u][2] = t.z; a[u][3] = t.w;
        }
        float acc[4][4];
#pragma unroll
        for (int j = 0; j < 4; ++j) {
            int o = og * 4 + j;
            float wx = W1[o * 3 + 0], wy = W1[o * 3 + 1], wz = W1[o * 3 + 2];
#pragma unroll
            for (int q = 0; q < 4; ++q)
                acc[q][j] = a[0][q] * wx + a[1][q] * wy + a[2][q] * wz;
        }
        store_B<4>(Bb, B1, og, pg, acc);
    }
    __syncthreads();
    layer_ln<128, true>(A, Bb, G1, E1, tid);
    __syncthreads();
    { // layer2: 128 -> 128
        float acc[4][4];
        gemm_acc<128, 4>(A, W2, og, pg, acc);
        store_B<4>(Bb, B2, og, pg, acc);
    }
    __syncthreads();
    layer_ln<128, true>(A, Bb, G2, E2, tid);
    __syncthreads();
    { // layer3: 128 -> 256
        float acc[4][8];
        gemm_acc<128, 8>(A, W3, og, pg, acc);
        store_B<8>(Bb, B3, og, pg, acc);
    }
    __syncthreads();
    layer_ln<256, true>(A, Bb, G3, E3, tid);
    __syncthreads();
    { // layer4: 256 -> 256
        float acc[4][8];
        gemm_acc<256, 8>(A, W4, og, pg, acc);
        store_B<8>(Bb, B4, og, pg, acc);
    }
    __syncthreads();
    layer_ln<256, false>(A, Bb, G4, E4, tid);
    __syncthreads();
    { // per-channel max over this block's 32 points, then device atomic max
        float m = -INFINITY;
#pragma unroll 4
        for (int p = 0; p < TILE; ++p) m = fmaxf(m, A[tid][p]);
        atomicMax(&maxkey[b * 256 + tid], fkey(m));
    }
}

// ---------------- kernel 2: ctx + time-embed + hypernet context -------------
__global__ __launch_bounds__(256)
void hyper_kernel(const unsigned* __restrict__ maxkey, const float* __restrict__ tt,
                  const float* __restrict__ HW1, const float* __restrict__ HB1,
                  const float* __restrict__ HG1, const float* __restrict__ HE1,
                  const float* __restrict__ HW2, const float* __restrict__ HB2,
                  const float* __restrict__ HG2, const float* __restrict__ HE2,
                  float* __restrict__ c_out) {
    __shared__ float xc[320];
    __shared__ float buf[256];
    __shared__ float rs[4], rq[4];
    const int b = blockIdx.x, tid = threadIdx.x;
    xc[tid] = funkey(maxkey[b * 256 + tid]);
    if (tid < 32) {
        float emb = expf((float)tid * (-logf(10000.f) / 31.f));
        float arg = tt[b] * emb;
        xc[256 + tid] = sinf(arg);
        xc[288 + tid] = cosf(arg);
    }
    __syncthreads();
    // layer1: 320 -> 256 (thread = output channel)
    float acc = HB1[tid];
    for (int i = 0; i < 320; i += 4) {
        float4 w = *(const float4*)&HW1[(size_t)tid * 320 + i];
        acc += xc[i] * w.x + xc[i + 1] * w.y + xc[i + 2] * w.z + xc[i + 3] * w.w;
    }
    float s = acc, q = acc * acc;
#pragma unroll
    for (int off = 32; off; off >>= 1) { s += __shfl_xor(s, off); q += __shfl_xor(q, off); }
    if ((tid & 63) == 0) { rs[tid >> 6] = s; rq[tid >> 6] = q; }
    __syncthreads();
    s = rs[0] + rs[1] + rs[2] + rs[3];
    q = rq[0] + rq[1] + rq[2] + rq[3];
    float mean = s * (1.f / 256), var = q * (1.f / 256) - mean * mean;
    float rstd = rsqrtf(var + 1e-5f);
    float h = gelu_exact((acc - mean) * rstd * HG1[tid] + HE1[tid]);
    __syncthreads();
    buf[tid] = h;
    __syncthreads();
    // layer2: 256 -> 256
    acc = HB2[tid];
    for (int i = 0; i < 256; i += 4) {
        float4 w = *(const float4*)&HW2[(size_t)tid * 256 + i];
        acc += buf[i] * w.x + buf[i + 1] * w.y + buf[i + 2] * w.z + buf[i + 3] * w.w;
    }
    s = acc; q = acc * acc;
#pragma unroll
    for (int off = 32; off; off >>= 1) { s += __shfl_xor(s, off); q += __shfl_xor(q, off); }
    if ((tid & 63) == 0) { rs[tid >> 6] = s; rq[tid >> 6] = q; }
    __syncthreads();
    s = rs[0] + rs[1] + rs[2] + rs[3];
    q = rq[0] + rq[1] + rq[2] + rq[3];
    mean = s * (1.f / 256); var = q * (1.f / 256) - mean * mean;
    rstd = rsqrtf(var + 1e-5f);
    c_out[b * 256 + tid] = gelu_exact((acc - mean) * rstd * HG2[tid] + HE2[tid]);
}

// ---------------- kernel 3: generate field weights + biases -----------------
// one task per wave: tasks 0..127 = w0 rows, 128..255 = w1 rows, 256..258 = w2
// rows, 259..261 = biases of layers 0..2. Lane = element index; 32 batches per
// lane in registers; F.normalize fused via wave reduction.
__device__ __forceinline__ void gen_row(float acc[32], const float (*cs)[256],
                                        const float* __restrict__ Wg,
                                        const float* __restrict__ Wgb, int f, bool valid) {
#pragma unroll
    for (int b = 0; b < 32; ++b) acc[b] = 0.f;
    if (!valid) return;
    for (int i = 0; i < 256; i += 4) {
        float4 w = *(const float4*)&Wg[(size_t)f * 256 + i];
#pragma unroll
        for (int b = 0; b < 32; ++b) {
            float4 cv = *(const float4*)&cs[b][i];
            acc[b] += cv.x * w.x + cv.y * w.y + cv.z * w.z + cv.w * w.w;
        }
    }
    float bias = Wgb[f];
#pragma unroll
    for (int b = 0; b < 32; ++b) acc[b] += bias;
}

__global__ __launch_bounds__(256)
void wgen_kernel(const float* __restrict__ c,
                 const float* __restrict__ WG0, const float* __restrict__ WGB0,
                 const float* __restrict__ BG0, const float* __restrict__ BGB0,
                 const float* __restrict__ WG1, const float* __restrict__ WGB1,
                 const float* __restrict__ BG1, const float* __restrict__ BGB1,
                 const float* __restrict__ WG2, const float* __restrict__ WGB2,
                 const float* __restrict__ BG2, const float* __restrict__ BGB2,
                 float* __restrict__ w0, float* __restrict__ w1, float* __restrict__ w2,
                 float* __restrict__ bb0, float* __restrict__ bb1, float* __restrict__ bb2) {
    __shared__ float cs[32][256];
    const int tid = threadIdx.x;
    for (int i = tid; i < 32 * 256; i += 256) cs[i >> 8][i & 255] = c[i];
    __syncthreads();
    const int wave = tid >> 6, lane = tid & 63;
    const int task = blockIdx.x * 4 + wave;
    if (task >= 262) return;

    float accA[32], accB[32];
    if (task < 259) { // weight rows
        int layer, o;
        if (task < 128) { layer = 0; o = task; }
        else if (task < 256) { layer = 1; o = task - 128; }
        else { layer = 2; o = task - 256; }
        const int din = (layer == 0) ? 63 : 128;
        const float* Wg = (layer == 0) ? WG0 : (layer == 1) ? WG1 : WG2;
        const float* Wgb = (layer == 0) ? WGB0 : (layer == 1) ? WGB1 : WGB2;
        const int eA = lane, eB = lane + 64;
        const bool vA = eA < din, vB = eB < din;
        gen_row(accA, cs, Wg, Wgb, o * din + eA, vA);
        gen_row(accB, cs, Wg, Wgb, o * din + eB, vB);
#pragma unroll
        for (int b = 0; b < 32; ++b) {
            float xa = vA ? accA[b] : 0.f, xb = vB ? accB[b] : 0.f;
            float sq = xa * xa + xb * xb;
#pragma unroll
            for (int off = 32; off; off >>= 1) sq += __shfl_xor(sq, off);
            float rn = 1.f / fmaxf(sqrtf(sq), 1e-12f);
            if (layer == 0) { // padded to 64, col 63 zeroed
                w0[((size_t)b * 128 + o) * 64 + eA] = vA ? accA[b] * rn : 0.f;
            } else if (layer == 1) {
                w1[((size_t)b * 128 + o) * 128 + eA] = accA[b] * rn;
                w1[((size_t)b * 128 + o) * 128 + eB] = accB[b] * rn;
            } else {
                w2[((size_t)b * 3 + o) * 128 + eA] = accA[b] * rn;
                w2[((size_t)b * 3 + o) * 128 + eB] = accB[b] * rn;
            }
        }
    } else { // bias rows
        const int layer = task - 259;
        const int dout = (layer == 2) ? 3 : 128;
        const float* Bg = (layer == 0) ? BG0 : (layer == 1) ? BG1 : BG2;
        const float* Bgb = (layer == 0) ? BGB0 : (layer == 1) ? BGB1 : BGB2;
        const int eA = lane, eB = lane + 64;
        gen_row(accA, cs, Bg, Bgb, eA, eA < dout);
        gen_row(accB, cs, Bg, Bgb, eB, eB < dout);
        float* dst = (layer == 0) ? bb0 : (layer == 1) ? bb1 : bb2;
#pragma unroll
        for (int b = 0; b < 32; ++b) {
            if (eA < dout) dst[b * dout + eA] = accA[b];
            if (eB < dout) dst[b * dout + eB] = accB[b];
        }
    }
}

// ---------------- kernel 4: Fourier PE + generated field MLP ----------------
__global__ __launch_bounds__(256)
void field_kernel(const float* __restrict__ points,
                  const float* __restrict__ w0, const float* __restrict__ bb0,
                  const float* __restrict__ w1, const float* __restrict__ bb1,
                  const float* __restrict__ w2, const float* __restrict__ bb2,
                  float* __restrict__ out) {
    __shared__ float A0[128][36];
    __shared__ float A1[128][36];
    const int b = blockIdx.x / NBLK;
    const int n0 = (blockIdx.x % NBLK) * TILE;
    const int tid = threadIdx.x;
    const int og = tid >> 3, pg = tid & 7;

    // stage position encoding, transposed; row 63 zero-padded
    for (int idx = tid; idx < 64 * TILE; idx += 256) {
        int cch = idx >> 5, p = idx & 31;
        float val = 0.f;
        if (cch < 3) {
            val = points[((size_t)(b * N_PTS) + n0 + p) * 3 + cch];
        } else if (cch < 63) {
            int k = (cch - 3) % 30;
            int d = k / 10, f = k % 10;
            float x = points[((size_t)(b * N_PTS) + n0 + p) * 3 + d];
            float arg = x * ((float)(1 << f) * 3.14159265358979323846f);
            val = (cch < 33) ? sinf(arg) : cosf(arg);
        }
        A0[cch][p] = val;
    }
    __syncthreads();
    { // layer0: 64(pad) -> 128, gelu
        float acc[4][4];
        gemm_acc<64, 4>(A0, w0 + (size_t)b * 128 * 64, og, pg, acc);
#pragma unroll
        for (int j = 0; j < 4; ++j) {
            float bv = bb0[b * 128 + og * 4 + j];
#pragma unroll
            for (int q = 0; q < 4; ++q)
                A1[og * 4 + j][pg * 4 + q] = gelu_exact(acc[q][j] + bv);
        }
    }
    __syncthreads();
    { // layer1: 128 -> 128, gelu
        float acc[4][4];
        gemm_acc<128, 4>(A1, w1 + (size_t)b * 128 * 128, og, pg, acc);
#pragma unroll
        for (int j = 0; j < 4; ++j) {
            float bv = bb1[b * 128 + og * 4 + j];
#pragma unroll
            for (int q = 0; q < 4; ++q)
                A0[og * 4 + j][pg * 4 + q] = gelu_exact(acc[q][j] + bv);
        }
    }
    __syncthreads();
    { // layer2: 128 -> 3
        const int p = tid & 31, o = tid >> 5;
        if (o < 3) {
            float acc = 0.f;
            const float* wr = w2 + ((size_t)b * 3 + o) * 128;
            for (int i = 0; i < 128; i += 4) {
                float4 w = *(const float4*)&wr[i];
                acc += A0[i][p] * w.x + A0[i + 1][p] * w.y + A0[i + 2][p] * w.z + A0[i + 3][p] * w.w;
            }
            out[((size_t)(b * N_PTS) + n0 + p) * 3 + o] = acc + bb2[b * 3 + o];
        }
    }
}

extern "C" void kernel_launch(void* const* d_in, const int* in_sizes, int n_in,
                              void* d_out, int out_size, void* d_ws, size_t ws_size,
                              hipStream_t stream) {
    const float* points = (const float*)d_in[0];
    const float* tt = (const float*)d_in[1];
    const float* pw1 = (const float*)d_in[2],  *pb1 = (const float*)d_in[3];
    const float* pg1 = (const float*)d_in[4],  *pe1 = (const float*)d_in[5];
    const float* pw2 = (const float*)d_in[6],  *pb2 = (const float*)d_in[7];
    const float* pg2 = (const float*)d_in[8],  *pe2 = (const float*)d_in[9];
    const float* pw3 = (const float*)d_in[10], *pb3 = (const float*)d_in[11];
    const float* pg3 = (const float*)d_in[12], *pe3 = (const float*)d_in[13];
    const float* pw4 = (const float*)d_in[14], *pb4 = (const float*)d_in[15];
    const float* pg4 = (const float*)d_in[16], *pe4 = (const float*)d_in[17];
    const float* hw1 = (const float*)d_in[18], *hb1 = (const float*)d_in[19];
    const float* hg1 = (const float*)d_in[20], *he1 = (const float*)d_in[21];
    const float* hw2 = (const float*)d_in[22], *hb2 = (const float*)d_in[23];
    const float* hg2 = (const float*)d_in[24], *he2 = (const float*)d_in[25];
    const float* wg0w = (const float*)d_in[26], *wg0b = (const float*)d_in[27];
    const float* bg0w = (const float*)d_in[28], *bg0b = (const float*)d_in[29];
    const float* wg1w = (const float*)d_in[30], *wg1b = (const float*)d_in[31];
    const float* bg1w = (const float*)d_in[32], *bg1b = (const float*)d_in[33];
    const float* wg2w = (const float*)d_in[34], *wg2b = (const float*)d_in[35];
    const float* bg2w = (const float*)d_in[36], *bg2b = (const float*)d_in[37];

    float* ws = (float*)d_ws;
    unsigned* maxkey = (unsigned*)d_ws;              // [32][256]
    float* c_buf = ws + 8192;                        // [32][256]
    float* w0 = c_buf + 8192;                        // [32][128][64]
    float* w1 = w0 + 32 * 128 * 64;                  // [32][128][128]
    float* w2 = w1 + 32 * 128 * 128;                 // [32][3][128]
    float* bb0 = w2 + 32 * 3 * 128;                  // [32][128]
    float* bb1 = bb0 + 32 * 128;                     // [32][128]
    float* bb2 = bb1 + 32 * 128;                     // [32][3]

    init_kernel<<<32, 256, 0, stream>>>(maxkey);
    pointnet_kernel<<<NBATCH * NBLK, 256, 0, stream>>>(
        points, pw1, pb1, pg1, pe1, pw2, pb2, pg2, pe2,
        pw3, pb3, pg3, pe3, pw4, pb4, pg4, pe4, maxkey);
    hyper_kernel<<<NBATCH, 256, 0, stream>>>(
        maxkey, tt, hw1, hb1, hg1, he1, hw2, hb2, hg2, he2, c_buf);
    wgen_kernel<<<66, 256, 0, stream>>>(
        c_buf, wg0w, wg0b, bg0w, bg0b, wg1w, wg1b, bg1w, bg1b,
        wg2w, wg2b, bg2w, bg2b, w0, w1, w2, bb0, bb1, bb2);
    field_kernel<<<NBATCH * NBLK, 256, 0, stream>>>(
        points, w0, bb0, w1, bb1, w2, bb2, (float*)d_out);
}

// Round 2
// 1554.397 us; speedup vs baseline: 2.1818x; 2.1818x over previous
//
#include <hip/hip_runtime.h>

typedef _Float16 f16;
typedef f16 f16x8 __attribute__((ext_vector_type(8)));
typedef float f32x4 __attribute__((ext_vector_type(4)));

#define N_PTS 16384
#define NBATCH 32
#define PTILE 64
#define PN_BLOCKS (N_PTS / PTILE) /* 256 */

__device__ __forceinline__ float gelu_exact(float x) {
    return 0.5f * x * (1.0f + erff(x * 0.70710678118654752440f));
}
__device__ __forceinline__ unsigned fkey(float x) {
    unsigned u = __float_as_uint(x);
    return (u & 0x80000000u) ? ~u : (u | 0x80000000u);
}
__device__ __forceinline__ float funkey(unsigned k) {
    return (k & 0x80000000u) ? __uint_as_float(k ^ 0x80000000u) : __uint_as_float(~k);
}

// ---------------------------------------------------------------------------
// Generic MFMA layer over a 64-point tile.
//   A:  [64][ACOLS] f16 activations, layout [pt][ch]  (ACOLS ≡ 4 mod 32 words)
//   Wk: LDS staging panel, rows DOUT x 32 k-columns, row stride 40 f16
//   Wg: global f16 weights [DOUT][DIN] row-major
// Wave w computes ALL 4 point-tiles x its own DOUT/4 output channels.
// MODE 0: +bias, LN, GELU, write A.  MODE 1: +bias, LN, channel-max -> atomic.
// MODE 2: +bias, GELU, write A (no LN; Gam/Bet unused).
// MFMA frags: a: lane holds A[m=l&15][k=ks*32+(l>>4)*8+j]
//             b: lane holds W[n=l&15(+tile)][k=...]  (B[k][n] = W^T)
//             d: lane reg r holds D[m=(l>>4)*4+r][n=l&15]
// ---------------------------------------------------------------------------
template<int ACOLS, int DIN, int DOUT, int MODE>
__device__ __forceinline__ void mfma_layer(
    f16 (*A)[ACOLS], f16* Wk,
    const f16* __restrict__ Wg, const float* __restrict__ Bias,
    const float* __restrict__ Gam, const float* __restrict__ Bet,
    float2 (*Pp)[4], unsigned* __restrict__ mk)
{
    constexpr int KS = DIN / 32, TN = DOUT / 64;
    const int tid = threadIdx.x;
    const int w = tid >> 6, lane = tid & 63;
    const int i15 = lane & 15, g = lane >> 4;

    f32x4 d[4][TN];
#pragma unroll
    for (int mt = 0; mt < 4; ++mt)
#pragma unroll
        for (int nt = 0; nt < TN; ++nt) d[mt][nt] = (f32x4){0.f, 0.f, 0.f, 0.f};

#pragma unroll 1
    for (int ks = 0; ks < KS; ++ks) {
        __syncthreads();  // everyone done reading previous Wk panel
        for (int v = tid; v < DOUT * 4; v += 256) {
            int row = v >> 2, seg = v & 3;
            *(f16x8*)&Wk[row * 40 + seg * 8] =
                *(const f16x8*)&Wg[(size_t)row * DIN + ks * 32 + seg * 8];
        }
        __syncthreads();
        f16x8 a[4];
#pragma unroll
        for (int mt = 0; mt < 4; ++mt)
            a[mt] = *(const f16x8*)&A[mt * 16 + i15][ks * 32 + g * 8];
#pragma unroll
        for (int nt = 0; nt < TN; ++nt) {
            f16x8 bf = *(const f16x8*)&Wk[(w * (TN * 16) + nt * 16 + i15) * 40 + g * 8];
#pragma unroll
            for (int mt = 0; mt < 4; ++mt)
                d[mt][nt] = __builtin_amdgcn_mfma_f32_16x16x32_f16(a[mt], bf, d[mt][nt], 0, 0, 0);
        }
    }

    float bias[TN], gam[TN], bet[TN];
#pragma unroll
    for (int nt = 0; nt < TN; ++nt) {
        int ch = w * (TN * 16) + nt * 16 + i15;
        bias[nt] = Bias[ch];
        if constexpr (MODE <= 1) { gam[nt] = Gam[ch]; bet[nt] = Bet[ch]; }
        else { gam[nt] = 0.f; bet[nt] = 0.f; }
    }
#pragma unroll
    for (int mt = 0; mt < 4; ++mt)
#pragma unroll
        for (int nt = 0; nt < TN; ++nt)
#pragma unroll
            for (int r = 0; r < 4; ++r) d[mt][nt][r] += bias[nt];

    if constexpr (MODE <= 1) {
        // ---- LayerNorm: partial sums over this wave's channel slice --------
#pragma unroll
        for (int mt = 0; mt < 4; ++mt)
#pragma unroll
            for (int r = 0; r < 4; ++r) {
                float ss = 0.f, qq = 0.f;
#pragma unroll
                for (int nt = 0; nt < TN; ++nt) {
                    float v = d[mt][nt][r];
                    ss += v; qq += v * v;
                }
#pragma unroll
                for (int m = 1; m <= 8; m <<= 1) {
                    ss += __shfl_xor(ss, m);
                    qq += __shfl_xor(qq, m);
                }
                if (i15 == 0) Pp[mt * 16 + g * 4 + r][w] = make_float2(ss, qq);
            }
        __syncthreads();
        float maxv[TN];
#pragma unroll
        for (int nt = 0; nt < TN; ++nt) maxv[nt] = -1e30f;
#pragma unroll
        for (int mt = 0; mt < 4; ++mt)
#pragma unroll
            for (int r = 0; r < 4; ++r) {
                int pt = mt * 16 + g * 4 + r;
                float2 p0 = Pp[pt][0], p1 = Pp[pt][1], p2 = Pp[pt][2], p3 = Pp[pt][3];
                float S = p0.x + p1.x + p2.x + p3.x;
                float Q = p0.y + p1.y + p2.y + p3.y;
                float mean = S * (1.f / DOUT);
                float var = Q * (1.f / DOUT) - mean * mean;
                float rstd = rsqrtf(var + 1e-5f);
#pragma unroll
                for (int nt = 0; nt < TN; ++nt) {
                    float y = (d[mt][nt][r] - mean) * rstd * gam[nt] + bet[nt];
                    if constexpr (MODE == 0) {
                        y = gelu_exact(y);
                        A[pt][w * (TN * 16) + nt * 16 + i15] = (f16)y;
                    } else {
                        maxv[nt] = fmaxf(maxv[nt], y);
                    }
                }
            }
        if constexpr (MODE == 1) {
#pragma unroll
            for (int nt = 0; nt < TN; ++nt) {
                maxv[nt] = fmaxf(maxv[nt], __shfl_xor(maxv[nt], 16));
                maxv[nt] = fmaxf(maxv[nt], __shfl_xor(maxv[nt], 32));
            }
            if (lane < 16) {
#pragma unroll
                for (int nt = 0; nt < TN; ++nt)
                    atomicMax(&mk[w * (TN * 16) + nt * 16 + i15], fkey(maxv[nt]));
            }
        }
    } else {
        __syncthreads();  // all waves finished reading A before overwrite
#pragma unroll
        for (int mt = 0; mt < 4; ++mt)
#pragma unroll
            for (int nt = 0; nt < TN; ++nt)
#pragma unroll
                for (int r = 0; r < 4; ++r) {
                    float y = gelu_exact(d[mt][nt][r]);
                    A[mt * 16 + g * 4 + r][w * (TN * 16) + nt * 16 + i15] = (f16)y;
                }
    }
    __syncthreads();  // layer output visible to all waves
}

// ---------------- kernel 0: init atomic-max keys ----------------------------
__global__ void init_kernel(unsigned* __restrict__ maxkey) {
    maxkey[blockIdx.x * 256 + threadIdx.x] = 0u;
}

// ---------------- kernel 0b: fp32 -> f16 weight conversion (+L1 K-pad) ------
__global__ void prep_kernel(const float* __restrict__ W1, const float* __restrict__ W2,
                            const float* __restrict__ W3, const float* __restrict__ W4,
                            f16* __restrict__ W1f, f16* __restrict__ W2f,
                            f16* __restrict__ W3f, f16* __restrict__ W4f) {
    int i = blockIdx.x * 256 + threadIdx.x;
    if (i < 128 * 32) {
        int r = i >> 5, c = i & 31;
        W1f[i] = (f16)(c < 3 ? W1[r * 3 + c] : 0.f);
    }
    int j = i - 128 * 32;
    if (j >= 0 && j < 128 * 128) W2f[j] = (f16)W2[j];
    int k = i - (128 * 32 + 128 * 128);
    if (k >= 0 && k < 256 * 128) W3f[k] = (f16)W3[k];
    int l = i - (128 * 32 + 128 * 128 + 256 * 128);
    if (l >= 0 && l < 256 * 256) W4f[l] = (f16)W4[l];
}

// ---------------- kernel 1: PointNet encoder (MFMA) -------------------------
__global__ __launch_bounds__(256)
void pointnet_kernel(const float* __restrict__ points,
                     const f16* __restrict__ W1f, const float* __restrict__ B1,
                     const float* __restrict__ G1, const float* __restrict__ E1,
                     const f16* __restrict__ W2f, const float* __restrict__ B2,
                     const float* __restrict__ G2, const float* __restrict__ E2,
                     const f16* __restrict__ W3f, const float* __restrict__ B3,
                     const float* __restrict__ G3, const float* __restrict__ E3,
                     const f16* __restrict__ W4f, const float* __restrict__ B4,
                     const float* __restrict__ G4, const float* __restrict__ E4,
                     unsigned* __restrict__ maxkey) {
    __shared__ __attribute__((aligned(16))) f16 A[PTILE][264];
    __shared__ __attribute__((aligned(16))) f16 Wk[256 * 40];
    __shared__ float2 Pp[PTILE][4];
    const int b = blockIdx.x / PN_BLOCKS;
    const int n0 = (blockIdx.x % PN_BLOCKS) * PTILE;
    const int tid = threadIdx.x;
    for (int i = tid; i < PTILE * 32; i += 256) {
        int p = i >> 5, c = i & 31;
        A[p][c] = (f16)(c < 3 ? points[((size_t)b * N_PTS + n0 + p) * 3 + c] : 0.f);
    }
    // (layer starts with __syncthreads before any A read)
    mfma_layer<264, 32, 128, 0>(A, Wk, W1f, B1, G1, E1, Pp, nullptr);
    mfma_layer<264, 128, 128, 0>(A, Wk, W2f, B2, G2, E2, Pp, nullptr);
    mfma_layer<264, 128, 256, 0>(A, Wk, W3f, B3, G3, E3, Pp, nullptr);
    mfma_layer<264, 256, 256, 1>(A, Wk, W4f, B4, G4, E4, Pp, maxkey + b * 256);
}

// ---------------- kernel 2: ctx + time-embed + hypernet context -------------
__global__ __launch_bounds__(256)
void hyper_kernel(const unsigned* __restrict__ maxkey, const float* __restrict__ tt,
                  const float* __restrict__ HW1, const float* __restrict__ HB1,
                  const float* __restrict__ HG1, const float* __restrict__ HE1,
                  const float* __restrict__ HW2, const float* __restrict__ HB2,
                  const float* __restrict__ HG2, const float* __restrict__ HE2,
                  float* __restrict__ c_out) {
    __shared__ float xc[320];
    __shared__ float buf[256];
    __shared__ float rs[4], rq[4];
    const int b = blockIdx.x, tid = threadIdx.x;
    xc[tid] = funkey(maxkey[b * 256 + tid]);
    if (tid < 32) {
        float emb = expf((float)tid * (-logf(10000.f) / 31.f));
        float arg = tt[b] * emb;
        xc[256 + tid] = sinf(arg);
        xc[288 + tid] = cosf(arg);
    }
    __syncthreads();
    float acc = HB1[tid];
    for (int i = 0; i < 320; i += 4) {
        float4 w = *(const float4*)&HW1[(size_t)tid * 320 + i];
        acc += xc[i] * w.x + xc[i + 1] * w.y + xc[i + 2] * w.z + xc[i + 3] * w.w;
    }
    float s = acc, q = acc * acc;
#pragma unroll
    for (int off = 32; off; off >>= 1) { s += __shfl_xor(s, off); q += __shfl_xor(q, off); }
    if ((tid & 63) == 0) { rs[tid >> 6] = s; rq[tid >> 6] = q; }
    __syncthreads();
    s = rs[0] + rs[1] + rs[2] + rs[3];
    q = rq[0] + rq[1] + rq[2] + rq[3];
    float mean = s * (1.f / 256), var = q * (1.f / 256) - mean * mean;
    float rstd = rsqrtf(var + 1e-5f);
    float h = gelu_exact((acc - mean) * rstd * HG1[tid] + HE1[tid]);
    __syncthreads();
    buf[tid] = h;
    __syncthreads();
    acc = HB2[tid];
    for (int i = 0; i < 256; i += 4) {
        float4 w = *(const float4*)&HW2[(size_t)tid * 256 + i];
        acc += buf[i] * w.x + buf[i + 1] * w.y + buf[i + 2] * w.z + buf[i + 3] * w.w;
    }
    s = acc; q = acc * acc;
#pragma unroll
    for (int off = 32; off; off >>= 1) { s += __shfl_xor(s, off); q += __shfl_xor(q, off); }
    if ((tid & 63) == 0) { rs[tid >> 6] = s; rq[tid >> 6] = q; }
    __syncthreads();
    s = rs[0] + rs[1] + rs[2] + rs[3];
    q = rq[0] + rq[1] + rq[2] + rq[3];
    mean = s * (1.f / 256); var = q * (1.f / 256) - mean * mean;
    rstd = rsqrtf(var + 1e-5f);
    c_out[b * 256 + tid] = gelu_exact((acc - mean) * rstd * HG2[tid] + HE2[tid]);
}

// ---------------- kernel 3: generate field weights + biases (f16 out) -------
__device__ __forceinline__ void gen_row(float acc[32], const float (*cs)[256],
                                        const float* __restrict__ Wg,
                                        const float* __restrict__ Wgb, int f, bool valid) {
#pragma unroll
    for (int b = 0; b < 32; ++b) acc[b] = 0.f;
    if (!valid) return;
    for (int i = 0; i < 256; i += 4) {
        float4 w = *(const float4*)&Wg[(size_t)f * 256 + i];
#pragma unroll
        for (int b = 0; b < 32; ++b) {
            float4 cv = *(const float4*)&cs[b][i];
            acc[b] += cv.x * w.x + cv.y * w.y + cv.z * w.z + cv.w * w.w;
        }
    }
    float bias = Wgb[f];
#pragma unroll
    for (int b = 0; b < 32; ++b) acc[b] += bias;
}

__global__ __launch_bounds__(256)
void wgen_kernel(const float* __restrict__ c,
                 const float* __restrict__ WG0, const float* __restrict__ WGB0,
                 const float* __restrict__ BG0, const float* __restrict__ BGB0,
                 const float* __restrict__ WG1, const float* __restrict__ WGB1,
                 const float* __restrict__ BG1, const float* __restrict__ BGB1,
                 const float* __restrict__ WG2, const float* __restrict__ WGB2,
                 const float* __restrict__ BG2, const float* __restrict__ BGB2,
                 f16* __restrict__ w0f, f16* __restrict__ w1f, f16* __restrict__ w2f,
                 float* __restrict__ bb0, float* __restrict__ bb1, float* __restrict__ bb2) {
    __shared__ float cs[32][256];
    const int tid = threadIdx.x;
    for (int i = tid; i < 32 * 256; i += 256) cs[i >> 8][i & 255] = c[i];
    __syncthreads();
    const int wave = tid >> 6, lane = tid & 63;
    const int task = blockIdx.x * 4 + wave;
    if (task >= 262) return;

    float accA[32], accB[32];
    if (task < 259) {
        int layer, o;
        if (task < 128) { layer = 0; o = task; }
        else if (task < 256) { layer = 1; o = task - 128; }
        else { layer = 2; o = task - 256; }
        const int din = (layer == 0) ? 63 : 128;
        const float* Wg = (layer == 0) ? WG0 : (layer == 1) ? WG1 : WG2;
        const float* Wgb = (layer == 0) ? WGB0 : (layer == 1) ? WGB1 : WGB2;
        const int eA = lane, eB = lane + 64;
        const bool vA = eA < din, vB = eB < din;
        gen_row(accA, cs, Wg, Wgb, o * din + eA, vA);
        gen_row(accB, cs, Wg, Wgb, o * din + eB, vB);
#pragma unroll
        for (int b = 0; b < 32; ++b) {
            float xa = vA ? accA[b] : 0.f, xb = vB ? accB[b] : 0.f;
            float sq = xa * xa + xb * xb;
#pragma unroll
            for (int off = 32; off; off >>= 1) sq += __shfl_xor(sq, off);
            float rn = 1.f / fmaxf(sqrtf(sq), 1e-12f);
            if (layer == 0) { // [128][64] f16, col 63 zeroed (K padded to 64)
                w0f[((size_t)b * 128 + o) * 64 + eA] = (f16)(vA ? accA[b] * rn : 0.f);
            } else if (layer == 1) {
                w1f[((size_t)b * 128 + o) * 128 + eA] = (f16)(accA[b] * rn);
                w1f[((size_t)b * 128 + o) * 128 + eB] = (f16)(accB[b] * rn);
            } else {
                w2f[((size_t)b * 3 + o) * 128 + eA] = (f16)(accA[b] * rn);
                w2f[((size_t)b * 3 + o) * 128 + eB] = (f16)(accB[b] * rn);
            }
        }
    } else {
        const int layer = task - 259;
        const int dout = (layer == 2) ? 3 : 128;
        const float* Bg = (layer == 0) ? BG0 : (layer == 1) ? BG1 : BG2;
        const float* Bgb = (layer == 0) ? BGB0 : (layer == 1) ? BGB1 : BGB2;
        const int eA = lane, eB = lane + 64;
        gen_row(accA, cs, Bg, Bgb, eA, eA < dout);
        gen_row(accB, cs, Bg, Bgb, eB, eB < dout);
        float* dst = (layer == 0) ? bb0 : (layer == 1) ? bb1 : bb2;
#pragma unroll
        for (int b = 0; b < 32; ++b) {
            if (eA < dout) dst[b * dout + eA] = accA[b];
            if (eB < dout) dst[b * dout + eB] = accB[b];
        }
    }
}

// ---------------- kernel 4: Fourier PE + generated field MLP (MFMA) ---------
__global__ __launch_bounds__(256)
void field_kernel(const float* __restrict__ points,
                  const f16* __restrict__ w0f, const float* __restrict__ bb0,
                  const f16* __restrict__ w1f, const float* __restrict__ bb1,
                  const f16* __restrict__ w2f, const float* __restrict__ bb2,
                  float* __restrict__ out) {
    __shared__ __attribute__((aligned(16))) f16 A[PTILE][136];
    __shared__ __attribute__((aligned(16))) f16 Wk[128 * 40];
    const int b = blockIdx.x / PN_BLOCKS;
    const int n0 = (blockIdx.x % PN_BLOCKS) * PTILE;
    const int tid = threadIdx.x;
    for (int i = tid; i < PTILE * 64; i += 256) {
        int p = i >> 6, c = i & 63;
        float val = 0.f;
        if (c < 3) {
            val = points[((size_t)b * N_PTS + n0 + p) * 3 + c];
        } else if (c < 63) {
            int k = (c - 3) % 30, dd = k / 10, f = k % 10;
            float x = points[((size_t)b * N_PTS + n0 + p) * 3 + dd];
            float arg = x * ((float)(1 << f) * 3.14159265358979323846f);
            val = (c < 33) ? sinf(arg) : cosf(arg);
        }
        A[p][c] = (f16)val;  // col 63 zero-pad
    }
    mfma_layer<136, 64, 128, 2>(A, Wk, w0f + (size_t)b * 128 * 64, bb0 + b * 128,
                                nullptr, nullptr, nullptr, nullptr);
    mfma_layer<136, 128, 128, 2>(A, Wk, w1f + (size_t)b * 128 * 128, bb1 + b * 128,
                                 nullptr, nullptr, nullptr, nullptr);
    // final 128 -> 3 (tiny; fp32 dot on f16 activations)
    if (tid < PTILE * 3) {
        int p = tid / 3, ch = tid % 3;
        const f16* wr = w2f + ((size_t)b * 3 + ch) * 128;
        float acc = 0.f;
        for (int k = 0; k < 128; k += 8) {
            f16x8 av = *(const f16x8*)&A[p][k];
            f16x8 wv = *(const f16x8*)&wr[k];
#pragma unroll
            for (int j = 0; j < 8; ++j) acc += (float)av[j] * (float)wv[j];
        }
        out[((size_t)b * N_PTS + n0 + p) * 3 + ch] = acc + bb2[b * 3 + ch];
    }
}

extern "C" void kernel_launch(void* const* d_in, const int* in_sizes, int n_in,
                              void* d_out, int out_size, void* d_ws, size_t ws_size,
                              hipStream_t stream) {
    const float* points = (const float*)d_in[0];
    const float* tt = (const float*)d_in[1];
    const float* pw1 = (const float*)d_in[2],  *pb1 = (const float*)d_in[3];
    const float* pg1 = (const float*)d_in[4],  *pe1 = (const float*)d_in[5];
    const float* pw2 = (const float*)d_in[6],  *pb2 = (const float*)d_in[7];
    const float* pg2 = (const float*)d_in[8],  *pe2 = (const float*)d_in[9];
    const float* pw3 = (const float*)d_in[10], *pb3 = (const float*)d_in[11];
    const float* pg3 = (const float*)d_in[12], *pe3 = (const float*)d_in[13];
    const float* pw4 = (const float*)d_in[14], *pb4 = (const float*)d_in[15];
    const float* pg4 = (const float*)d_in[16], *pe4 = (const float*)d_in[17];
    const float* hw1 = (const float*)d_in[18], *hb1 = (const float*)d_in[19];
    const float* hg1 = (const float*)d_in[20], *he1 = (const float*)d_in[21];
    const float* hw2 = (const float*)d_in[22], *hb2 = (const float*)d_in[23];
    const float* hg2 = (const float*)d_in[24], *he2 = (const float*)d_in[25];
    const float* wg0w = (const float*)d_in[26], *wg0b = (const float*)d_in[27];
    const float* bg0w = (const float*)d_in[28], *bg0b = (const float*)d_in[29];
    const float* wg1w = (const float*)d_in[30], *wg1b = (const float*)d_in[31];
    const float* bg1w = (const float*)d_in[32], *bg1b = (const float*)d_in[33];
    const float* wg2w = (const float*)d_in[34], *wg2b = (const float*)d_in[35];
    const float* bg2w = (const float*)d_in[36], *bg2b = (const float*)d_in[37];

    // ---- workspace layout ----
    char* p = (char*)d_ws;
    unsigned* maxkey = (unsigned*)p;           p += 8192 * 4;     // [32][256]
    float* c_buf = (float*)p;                  p += 8192 * 4;     // [32][256]
    float* bb0 = (float*)p;                    p += 4096 * 4;
    float* bb1 = (float*)p;                    p += 4096 * 4;
    float* bb2 = (float*)p;                    p += 96 * 4 + 64;
    f16* W1f = (f16*)p;                        p += 128 * 32 * 2;
    f16* W2f = (f16*)p;                        p += 128 * 128 * 2;
    f16* W3f = (f16*)p;                        p += 256 * 128 * 2;
    f16* W4f = (f16*)p;                        p += 256 * 256 * 2;
    f16* w0f = (f16*)p;                        p += (size_t)32 * 128 * 64 * 2;
    f16* w1f = (f16*)p;                        p += (size_t)32 * 128 * 128 * 2;
    f16* w2f = (f16*)p;                        p += (size_t)32 * 3 * 128 * 2;

    init_kernel<<<32, 256, 0, stream>>>(maxkey);
    prep_kernel<<<464, 256, 0, stream>>>(pw1, pw2, pw3, pw4, W1f, W2f, W3f, W4f);
    pointnet_kernel<<<NBATCH * PN_BLOCKS, 256, 0, stream>>>(
        points, W1f, pb1, pg1, pe1, W2f, pb2, pg2, pe2,
        W3f, pb3, pg3, pe3, W4f, pb4, pg4, pe4, maxkey);
    hyper_kernel<<<NBATCH, 256, 0, stream>>>(
        maxkey, tt, hw1, hb1, hg1, he1, hw2, hb2, hg2, he2, c_buf);
    wgen_kernel<<<66, 256, 0, stream>>>(
        c_buf, wg0w, wg0b, bg0w, bg0b, wg1w, wg1b, bg1w, bg1b,
        wg2w, wg2b, bg2w, bg2b, w0f, w1f, w2f, bb0, bb1, bb2);
    field_kernel<<<NBATCH * PN_BLOCKS, 256, 0, stream>>>(
        points, w0f, bb0, w1f, bb1, w2f, bb2, (float*)d_out);
}

// Round 4
// 831.670 us; speedup vs baseline: 4.0779x; 1.8690x over previous
//
#include <hip/hip_runtime.h>

typedef _Float16 f16;
typedef f16 f16x8 __attribute__((ext_vector_type(8)));
typedef f16 f16x4 __attribute__((ext_vector_type(4)));
typedef float f32x4 __attribute__((ext_vector_type(4)));

#define N_PTS 16384
#define NBATCH 32
#define PTILE 64
#define PN_BLOCKS (N_PTS / PTILE) /* 256 */

__device__ __forceinline__ float gelu_exact(float x) {
    return 0.5f * x * (1.0f + erff(x * 0.70710678118654752440f));
}
// tanh-form GELU via sigmoid identity: 0.5x(1+tanh(y)) = x*sigma(2y)
__device__ __forceinline__ float gelu_fast(float x) {
    float u = x * x;
    float t = x * fmaf(u, 0.07135481627f, 1.5957691216f);
    float e = __expf(-t);
    return __fdividef(x, 1.f + e);
}
__device__ __forceinline__ unsigned fkey(float x) {
    unsigned u = __float_as_uint(x);
    return (u & 0x80000000u) ? ~u : (u | 0x80000000u);
}
__device__ __forceinline__ float funkey(unsigned k) {
    return (k & 0x80000000u) ? __uint_as_float(k ^ 0x80000000u) : __uint_as_float(~k);
}

// ---------------------------------------------------------------------------
// Swapped-operand MFMA layer over a 64-point tile: D[ch][pt] = W * A^T.
//   A: [64][ACOLS] f16 activations, [pt][ch], ACOLS ≡ 4 mod 16 words pad
//   Wg: global f16 weights [DOUT][DIN] row-major (read straight from L1/L2)
// Wave w owns channel slice [w*DOUT/4, (w+1)*DOUT/4), all 4 point tiles.
// d[nt][mt]: reg r -> ch=(w*TN+mt)*16+(l>>4)*4+r, pt=nt*16+(l&15).
// MODE 0: +bias,LN,GELU -> A.  MODE 1: +bias,LN, channel-max -> atomic.
// MODE 2: +bias,GELU -> A (no LN).
// ---------------------------------------------------------------------------
template<int ACOLS, int DIN, int DOUT, int MODE>
__device__ __forceinline__ void mfma_layerT(
    f16 (*A)[ACOLS],
    const f16* __restrict__ Wg, const float* __restrict__ Bias,
    const float* __restrict__ Gam, const float* __restrict__ Bet,
    float2 (*Pp)[4], unsigned* __restrict__ mk)
{
    constexpr int KS = DIN / 32, TN = DOUT / 64;
    const int tid = threadIdx.x;
    const int w = tid >> 6, lane = tid & 63;
    const int i15 = lane & 15, g = lane >> 4;

    f32x4 d[4][TN];
#pragma unroll
    for (int nt = 0; nt < 4; ++nt)
#pragma unroll
        for (int mt = 0; mt < TN; ++mt) d[nt][mt] = (f32x4){0.f, 0.f, 0.f, 0.f};

#pragma unroll 2
    for (int ks = 0; ks < KS; ++ks) {
        f16x8 wf[TN];
#pragma unroll
        for (int mt = 0; mt < TN; ++mt)
            wf[mt] = *(const f16x8*)&Wg[(size_t)((w * TN + mt) * 16 + i15) * DIN + ks * 32 + g * 8];
#pragma unroll
        for (int nt = 0; nt < 4; ++nt) {
            f16x8 af = *(const f16x8*)&A[nt * 16 + i15][ks * 32 + g * 8];
#pragma unroll
            for (int mt = 0; mt < TN; ++mt)
                d[nt][mt] = __builtin_amdgcn_mfma_f32_16x16x32_f16(wf[mt], af, d[nt][mt], 0, 0, 0);
        }
    }

    float bi[TN][4], ga[TN][4], be[TN][4];
#pragma unroll
    for (int mt = 0; mt < TN; ++mt) {
        int cb = (w * TN + mt) * 16 + g * 4;
        *(float4*)bi[mt] = *(const float4*)&Bias[cb];
        if constexpr (MODE <= 1) {
            *(float4*)ga[mt] = *(const float4*)&Gam[cb];
            *(float4*)be[mt] = *(const float4*)&Bet[cb];
        }
    }
#pragma unroll
    for (int nt = 0; nt < 4; ++nt)
#pragma unroll
        for (int mt = 0; mt < TN; ++mt)
#pragma unroll
            for (int r = 0; r < 4; ++r) d[nt][mt][r] += bi[mt][r];

    if constexpr (MODE <= 1) {
        // per-point LN: wave-partial = in-lane sum over (mt,r) + 2 shuffles
#pragma unroll
        for (int nt = 0; nt < 4; ++nt) {
            float ss = 0.f, qq = 0.f;
#pragma unroll
            for (int mt = 0; mt < TN; ++mt)
#pragma unroll
                for (int r = 0; r < 4; ++r) {
                    float v = d[nt][mt][r];
                    ss += v; qq += v * v;
                }
            ss += __shfl_xor(ss, 16); qq += __shfl_xor(qq, 16);
            ss += __shfl_xor(ss, 32); qq += __shfl_xor(qq, 32);
            if (g == 0) Pp[nt * 16 + i15][w] = make_float2(ss, qq);
        }
        __syncthreads();  // also guarantees all ks-loop A reads are done
        float mx[TN][4];
        if constexpr (MODE == 1) {
#pragma unroll
            for (int mt = 0; mt < TN; ++mt)
#pragma unroll
                for (int r = 0; r < 4; ++r) mx[mt][r] = -1e30f;
        }
#pragma unroll
        for (int nt = 0; nt < 4; ++nt) {
            int pt = nt * 16 + i15;
            float4 pa = *(const float4*)&Pp[pt][0];
            float4 pb = *(const float4*)&Pp[pt][2];
            float S = pa.x + pa.z + pb.x + pb.z;
            float Q = pa.y + pa.w + pb.y + pb.w;
            float mean = S * (1.f / DOUT);
            float var = Q * (1.f / DOUT) - mean * mean;
            float rstd = rsqrtf(var + 1e-5f);
#pragma unroll
            for (int mt = 0; mt < TN; ++mt) {
                if constexpr (MODE == 0) {
                    f16x4 pk;
#pragma unroll
                    for (int r = 0; r < 4; ++r) {
                        float y = (d[nt][mt][r] - mean) * rstd * ga[mt][r] + be[mt][r];
                        pk[r] = (f16)gelu_fast(y);
                    }
                    *(f16x4*)&A[pt][(w * TN + mt) * 16 + g * 4] = pk;
                } else {
#pragma unroll
                    for (int r = 0; r < 4; ++r) {
                        float y = (d[nt][mt][r] - mean) * rstd * ga[mt][r] + be[mt][r];
                        mx[mt][r] = fmaxf(mx[mt][r], y);
                    }
                }
            }
        }
        if constexpr (MODE == 0) {
            __syncthreads();
        } else {
#pragma unroll
            for (int mt = 0; mt < TN; ++mt)
#pragma unroll
                for (int r = 0; r < 4; ++r) {
                    float m = mx[mt][r];
                    m = fmaxf(m, __shfl_xor(m, 1));
                    m = fmaxf(m, __shfl_xor(m, 2));
                    m = fmaxf(m, __shfl_xor(m, 4));
                    m = fmaxf(m, __shfl_xor(m, 8));
                    mx[mt][r] = m;
                }
            if (i15 == 0) {
#pragma unroll
                for (int mt = 0; mt < TN; ++mt)
#pragma unroll
                    for (int r = 0; r < 4; ++r)
                        atomicMax(&mk[(w * TN + mt) * 16 + g * 4 + r], fkey(mx[mt][r]));
            }
        }
    } else {
        __syncthreads();  // all waves done reading A
#pragma unroll
        for (int nt = 0; nt < 4; ++nt) {
            int pt = nt * 16 + i15;
#pragma unroll
            for (int mt = 0; mt < TN; ++mt) {
                f16x4 pk;
#pragma unroll
                for (int r = 0; r < 4; ++r)
                    pk[r] = (f16)gelu_fast(d[nt][mt][r]);
                *(f16x4*)&A[pt][(w * TN + mt) * 16 + g * 4] = pk;
            }
        }
        __syncthreads();
    }
}

// ---------------- kernel 0: init atomic-max keys ----------------------------
__global__ void init_kernel(unsigned* __restrict__ maxkey) {
    maxkey[blockIdx.x * 256 + threadIdx.x] = 0u;
}

// ---------------- kernel 0b: fp32 -> f16 weight conversion (+L1 K-pad) ------
__global__ void prep_kernel(const float* __restrict__ W1, const float* __restrict__ W2,
                            const float* __restrict__ W3, const float* __restrict__ W4,
                            f16* __restrict__ W1f, f16* __restrict__ W2f,
                            f16* __restrict__ W3f, f16* __restrict__ W4f) {
    int i = blockIdx.x * 256 + threadIdx.x;
    if (i < 128 * 32) {
        int r = i >> 5, c = i & 31;
        W1f[i] = (f16)(c < 3 ? W1[r * 3 + c] : 0.f);
    }
    int j = i - 128 * 32;
    if (j >= 0 && j < 128 * 128) W2f[j] = (f16)W2[j];
    int k = i - (128 * 32 + 128 * 128);
    if (k >= 0 && k < 256 * 128) W3f[k] = (f16)W3[k];
    int l = i - (128 * 32 + 128 * 128 + 256 * 128);
    if (l >= 0 && l < 256 * 256) W4f[l] = (f16)W4[l];
}

// ---------------- kernel 1: PointNet encoder (MFMA, swapped) ----------------
__global__ __launch_bounds__(256, 3)
void pointnet_kernel(const float* __restrict__ points,
                     const f16* __restrict__ W1f, const float* __restrict__ B1,
                     const float* __restrict__ G1, const float* __restrict__ E1,
                     const f16* __restrict__ W2f, const float* __restrict__ B2,
                     const float* __restrict__ G2, const float* __restrict__ E2,
                     const f16* __restrict__ W3f, const float* __restrict__ B3,
                     const float* __restrict__ G3, const float* __restrict__ E3,
                     const f16* __restrict__ W4f, const float* __restrict__ B4,
                     const float* __restrict__ G4, const float* __restrict__ E4,
                     unsigned* __restrict__ maxkey) {
    __shared__ __attribute__((aligned(16))) f16 A[PTILE][264];
    __shared__ float2 Pp[PTILE][4];
    const int b = blockIdx.x / PN_BLOCKS;
    const int n0 = (blockIdx.x % PN_BLOCKS) * PTILE;
    const int tid = threadIdx.x;
    for (int i = tid; i < PTILE * 32; i += 256) {
        int p = i >> 5, c = i & 31;
        A[p][c] = (f16)(c < 3 ? points[((size_t)b * N_PTS + n0 + p) * 3 + c] : 0.f);
    }
    __syncthreads();
    mfma_layerT<264, 32, 128, 0>(A, W1f, B1, G1, E1, Pp, nullptr);
    mfma_layerT<264, 128, 128, 0>(A, W2f, B2, G2, E2, Pp, nullptr);
    mfma_layerT<264, 128, 256, 0>(A, W3f, B3, G3, E3, Pp, nullptr);
    mfma_layerT<264, 256, 256, 1>(A, W4f, B4, G4, E4, Pp, maxkey + b * 256);
}

// ---------------- kernel 2: ctx + time-embed + hypernet context -------------
__global__ __launch_bounds__(256)
void hyper_kernel(const unsigned* __restrict__ maxkey, const float* __restrict__ tt,
                  const float* __restrict__ HW1, const float* __restrict__ HB1,
                  const float* __restrict__ HG1, const float* __restrict__ HE1,
                  const float* __restrict__ HW2, const float* __restrict__ HB2,
                  const float* __restrict__ HG2, const float* __restrict__ HE2,
                  float* __restrict__ c_out) {
    __shared__ float xc[320];
    __shared__ float buf[256];
    __shared__ float rs[4], rq[4];
    const int b = blockIdx.x, tid = threadIdx.x;
    xc[tid] = funkey(maxkey[b * 256 + tid]);
    if (tid < 32) {
        float emb = expf((float)tid * (-logf(10000.f) / 31.f));
        float arg = tt[b] * emb;
        xc[256 + tid] = sinf(arg);
        xc[288 + tid] = cosf(arg);
    }
    __syncthreads();
    float acc = HB1[tid];
    for (int i = 0; i < 320; i += 4) {
        float4 w = *(const float4*)&HW1[(size_t)tid * 320 + i];
        acc += xc[i] * w.x + xc[i + 1] * w.y + xc[i + 2] * w.z + xc[i + 3] * w.w;
    }
    float s = acc, q = acc * acc;
#pragma unroll
    for (int off = 32; off; off >>= 1) { s += __shfl_xor(s, off); q += __shfl_xor(q, off); }
    if ((tid & 63) == 0) { rs[tid >> 6] = s; rq[tid >> 6] = q; }
    __syncthreads();
    s = rs[0] + rs[1] + rs[2] + rs[3];
    q = rq[0] + rq[1] + rq[2] + rq[3];
    float mean = s * (1.f / 256), var = q * (1.f / 256) - mean * mean;
    float rstd = rsqrtf(var + 1e-5f);
    float h = gelu_exact((acc - mean) * rstd * HG1[tid] + HE1[tid]);
    __syncthreads();
    buf[tid] = h;
    __syncthreads();
    acc = HB2[tid];
    for (int i = 0; i < 256; i += 4) {
        float4 w = *(const float4*)&HW2[(size_t)tid * 256 + i];
        acc += buf[i] * w.x + buf[i + 1] * w.y + buf[i + 2] * w.z + buf[i + 3] * w.w;
    }
    s = acc; q = acc * acc;
#pragma unroll
    for (int off = 32; off; off >>= 1) { s += __shfl_xor(s, off); q += __shfl_xor(q, off); }
    if ((tid & 63) == 0) { rs[tid >> 6] = s; rq[tid >> 6] = q; }
    __syncthreads();
    s = rs[0] + rs[1] + rs[2] + rs[3];
    q = rq[0] + rq[1] + rq[2] + rq[3];
    mean = s * (1.f / 256); var = q * (1.f / 256) - mean * mean;
    rstd = rsqrtf(var + 1e-5f);
    c_out[b * 256 + tid] = gelu_exact((acc - mean) * rstd * HG2[tid] + HE2[tid]);
}

// ---------------- kernel 3: generate field weights + biases (f16 out) -------
__device__ __forceinline__ void gen_row(float acc[32], const float (*cs)[256],
                                        const float* __restrict__ Wg,
                                        const float* __restrict__ Wgb, int f, bool valid) {
#pragma unroll
    for (int b = 0; b < 32; ++b) acc[b] = 0.f;
    if (!valid) return;
    for (int i = 0; i < 256; i += 4) {
        float4 w = *(const float4*)&Wg[(size_t)f * 256 + i];
#pragma unroll
        for (int b = 0; b < 32; ++b) {
            float4 cv = *(const float4*)&cs[b][i];
            acc[b] += cv.x * w.x + cv.y * w.y + cv.z * w.z + cv.w * w.w;
        }
    }
    float bias = Wgb[f];
#pragma unroll
    for (int b = 0; b < 32; ++b) acc[b] += bias;
}

__global__ __launch_bounds__(256)
void wgen_kernel(const float* __restrict__ c,
                 const float* __restrict__ WG0, const float* __restrict__ WGB0,
                 const float* __restrict__ BG0, const float* __restrict__ BGB0,
                 const float* __restrict__ WG1, const float* __restrict__ WGB1,
                 const float* __restrict__ BG1, const float* __restrict__ BGB1,
                 const float* __restrict__ WG2, const float* __restrict__ WGB2,
                 const float* __restrict__ BG2, const float* __restrict__ BGB2,
                 f16* __restrict__ w0f, f16* __restrict__ w1f, f16* __restrict__ w2f,
                 float* __restrict__ bb0, float* __restrict__ bb1, float* __restrict__ bb2) {
    __shared__ float cs[32][256];
    const int tid = threadIdx.x;
    for (int i = tid; i < 32 * 256; i += 256) cs[i >> 8][i & 255] = c[i];
    __syncthreads();
    const int wave = tid >> 6, lane = tid & 63;
    const int task = blockIdx.x * 4 + wave;
    if (task >= 262) return;

    float accA[32], accB[32];
    if (task < 259) {
        int layer, o;
        if (task < 128) { layer = 0; o = task; }
        else if (task < 256) { layer = 1; o = task - 128; }
        else { layer = 2; o = task - 256; }
        const int din = (layer == 0) ? 63 : 128;
        const float* Wg = (layer == 0) ? WG0 : (layer == 1) ? WG1 : WG2;
        const float* Wgb = (layer == 0) ? WGB0 : (layer == 1) ? WGB1 : WGB2;
        const int eA = lane, eB = lane + 64;
        const bool vA = eA < din, vB = eB < din;
        gen_row(accA, cs, Wg, Wgb, o * din + eA, vA);
        gen_row(accB, cs, Wg, Wgb, o * din + eB, vB);
#pragma unroll
        for (int b = 0; b < 32; ++b) {
            float xa = vA ? accA[b] : 0.f, xb = vB ? accB[b] : 0.f;
            float sq = xa * xa + xb * xb;
#pragma unroll
            for (int off = 32; off; off >>= 1) sq += __shfl_xor(sq, off);
            float rn = 1.f / fmaxf(sqrtf(sq), 1e-12f);
            if (layer == 0) { // [128][64] f16, col 63 zeroed (K padded to 64)
                w0f[((size_t)b * 128 + o) * 64 + eA] = (f16)(vA ? accA[b] * rn : 0.f);
            } else if (layer == 1) {
                w1f[((size_t)b * 128 + o) * 128 + eA] = (f16)(accA[b] * rn);
                w1f[((size_t)b * 128 + o) * 128 + eB] = (f16)(accB[b] * rn);
            } else {
                w2f[((size_t)b * 3 + o) * 128 + eA] = (f16)(accA[b] * rn);
                w2f[((size_t)b * 3 + o) * 128 + eB] = (f16)(accB[b] * rn);
            }
        }
    } else {
        const int layer = task - 259;
        const int dout = (layer == 2) ? 3 : 128;
        const float* Bg = (layer == 0) ? BG0 : (layer == 1) ? BG1 : BG2;
        const float* Bgb = (layer == 0) ? BGB0 : (layer == 1) ? BGB1 : BGB2;
        const int eA = lane, eB = lane + 64;
        gen_row(accA, cs, Bg, Bgb, eA, eA < dout);
        gen_row(accB, cs, Bg, Bgb, eB, eB < dout);
        float* dst = (layer == 0) ? bb0 : (layer == 1) ? bb1 : bb2;
#pragma unroll
        for (int b = 0; b < 32; ++b) {
            if (eA < dout) dst[b * dout + eA] = accA[b];
            if (eB < dout) dst[b * dout + eB] = accB[b];
        }
    }
}

// ---------------- kernel 4: Fourier PE + generated field MLP (MFMA) ---------
__global__ __launch_bounds__(256, 4)
void field_kernel(const float* __restrict__ points,
                  const f16* __restrict__ w0f, const float* __restrict__ bb0,
                  const f16* __restrict__ w1f, const float* __restrict__ bb1,
                  const f16* __restrict__ w2f, const float* __restrict__ bb2,
                  float* __restrict__ out) {
    __shared__ __attribute__((aligned(16))) f16 A[PTILE][136];
    const int b = blockIdx.x / PN_BLOCKS;
    const int n0 = (blockIdx.x % PN_BLOCKS) * PTILE;
    const int tid = threadIdx.x;
    {   // thread t: point p = t>>2, column quarter q = t&3 (16 cols each)
        const int p = tid >> 2, q = tid & 3;
        float xyz[3];
#pragma unroll
        for (int dd = 0; dd < 3; ++dd)
            xyz[dd] = points[((size_t)b * N_PTS + n0 + p) * 3 + dd];
#pragma unroll
        for (int j = 0; j < 16; ++j) {
            int c = q * 16 + j;
            float val;
            if (c < 3) val = xyz[c];
            else if (c < 33) {
                int k = c - 3, dd = k / 10, f = k % 10;
                val = __sinf(xyz[dd] * ((float)(1 << f) * 3.14159265358979f));
            } else if (c < 63) {
                int k = c - 33, dd = k / 10, f = k % 10;
                val = __cosf(xyz[dd] * ((float)(1 << f) * 3.14159265358979f));
            } else val = 0.f;
            A[p][c] = (f16)val;
        }
    }
    __syncthreads();
    mfma_layerT<136, 64, 128, 2>(A, w0f + (size_t)b * 128 * 64, bb0 + b * 128,
                                 nullptr, nullptr, nullptr, nullptr);
    mfma_layerT<136, 128, 128, 2>(A, w1f + (size_t)b * 128 * 128, bb1 + b * 128,
                                  nullptr, nullptr, nullptr, nullptr);
    // final 128 -> 3 (tiny; fp32 dot on f16 activations)
    if (tid < PTILE * 3) {
        int p = tid / 3, ch = tid % 3;
        const f16* wr = w2f + ((size_t)b * 3 + ch) * 128;
        float acc = 0.f;
        for (int k = 0; k < 128; k += 8) {
            f16x8 av = *(const f16x8*)&A[p][k];
            f16x8 wv = *(const f16x8*)&wr[k];
#pragma unroll
            for (int j = 0; j < 8; ++j) acc += (float)av[j] * (float)wv[j];
        }
        out[((size_t)b * N_PTS + n0 + p) * 3 + ch] = acc + bb2[b * 3 + ch];
    }
}

extern "C" void kernel_launch(void* const* d_in, const int* in_sizes, int n_in,
                              void* d_out, int out_size, void* d_ws, size_t ws_size,
                              hipStream_t stream) {
    const float* points = (const float*)d_in[0];
    const float* tt = (const float*)d_in[1];
    const float* pw1 = (const float*)d_in[2],  *pb1 = (const float*)d_in[3];
    const float* pg1 = (const float*)d_in[4],  *pe1 = (const float*)d_in[5];
    const float* pw2 = (const float*)d_in[6],  *pb2 = (const float*)d_in[7];
    const float* pg2 = (const float*)d_in[8],  *pe2 = (const float*)d_in[9];
    const float* pw3 = (const float*)d_in[10], *pb3 = (const float*)d_in[11];
    const float* pg3 = (const float*)d_in[12], *pe3 = (const float*)d_in[13];
    const float* pw4 = (const float*)d_in[14], *pb4 = (const float*)d_in[15];
    const float* pg4 = (const float*)d_in[16], *pe4 = (const float*)d_in[17];
    const float* hw1 = (const float*)d_in[18], *hb1 = (const float*)d_in[19];
    const float* hg1 = (const float*)d_in[20], *he1 = (const float*)d_in[21];
    const float* hw2 = (const float*)d_in[22], *hb2 = (const float*)d_in[23];
    const float* hg2 = (const float*)d_in[24], *he2 = (const float*)d_in[25];
    const float* wg0w = (const float*)d_in[26], *wg0b = (const float*)d_in[27];
    const float* bg0w = (const float*)d_in[28], *bg0b = (const float*)d_in[29];
    const float* wg1w = (const float*)d_in[30], *wg1b = (const float*)d_in[31];
    const float* bg1w = (const float*)d_in[32], *bg1b = (const float*)d_in[33];
    const float* wg2w = (const float*)d_in[34], *wg2b = (const float*)d_in[35];
    const float* bg2w = (const float*)d_in[36], *bg2b = (const float*)d_in[37];

    // ---- workspace layout ----
    char* p = (char*)d_ws;
    unsigned* maxkey = (unsigned*)p;           p += 8192 * 4;     // [32][256]
    float* c_buf = (float*)p;                  p += 8192 * 4;     // [32][256]
    float* bb0 = (float*)p;                    p += 4096 * 4;
    float* bb1 = (float*)p;                    p += 4096 * 4;
    float* bb2 = (float*)p;                    p += 96 * 4 + 64;
    f16* W1f = (f16*)p;                        p += 128 * 32 * 2;
    f16* W2f = (f16*)p;                        p += 128 * 128 * 2;
    f16* W3f = (f16*)p;                        p += 256 * 128 * 2;
    f16* W4f = (f16*)p;                        p += 256 * 256 * 2;
    f16* w0f = (f16*)p;                        p += (size_t)32 * 128 * 64 * 2;
    f16* w1f = (f16*)p;                        p += (size_t)32 * 128 * 128 * 2;
    f16* w2f = (f16*)p;                        p += (size_t)32 * 3 * 128 * 2;

    init_kernel<<<32, 256, 0, stream>>>(maxkey);
    prep_kernel<<<464, 256, 0, stream>>>(pw1, pw2, pw3, pw4, W1f, W2f, W3f, W4f);
    pointnet_kernel<<<NBATCH * PN_BLOCKS, 256, 0, stream>>>(
        points, W1f, pb1, pg1, pe1, W2f, pb2, pg2, pe2,
        W3f, pb3, pg3, pe3, W4f, pb4, pg4, pe4, maxkey);
    hyper_kernel<<<NBATCH, 256, 0, stream>>>(
        maxkey, tt, hw1, hb1, hg1, he1, hw2, hb2, hg2, he2, c_buf);
    wgen_kernel<<<66, 256, 0, stream>>>(
        c_buf, wg0w, wg0b, bg0w, bg0b, wg1w, wg1b, bg1w, bg1b,
        wg2w, wg2b, bg2w, bg2b, w0f, w1f, w2f, bb0, bb1, bb2);
    field_kernel<<<NBATCH * PN_BLOCKS, 256, 0, stream>>>(
        points, w0f, bb0, w1f, bb1, w2f, bb2, (float*)d_out);
}

// Round 7
// 775.312 us; speedup vs baseline: 4.3743x; 1.0727x over previous
//
#include <hip/hip_runtime.h>
#include <hip/hip_fp16.h>

typedef _Float16 f16;
typedef f16 f16x8 __attribute__((ext_vector_type(8)));
typedef f16 f16x4 __attribute__((ext_vector_type(4)));
typedef float f32x4 __attribute__((ext_vector_type(4)));

#define N_PTS 16384
#define NBATCH 32
#define PTILE 64
#define PN_BLOCKS (N_PTS / PTILE) /* 256 */

__device__ __forceinline__ float gelu_exact(float x) {
    return 0.5f * x * (1.0f + erff(x * 0.70710678118654752440f));
}
// packed tanh-GELU: x*sigmoid(1.5958x+0.07135x^3), exp2-folded, in half2
__device__ __forceinline__ __half2 gelu_pk(__half2 x) {
    const __half2 c1 = __float2half2_rn(-0.10293984f);   // -log2(e)*0.07135481627
    const __half2 c2 = __float2half2_rn(-2.30220830f);   // -log2(e)*1.59576912
    const __half2 one = __float2half2_rn(1.0f);
    __half2 u = __hmul2(x, x);
    __half2 t = __hmul2(x, __hfma2(u, c1, c2));
    __half2 e = h2exp2(t);                               // x<<0: e->inf -> y=0; x>>0: e->0 -> y=x
    return __hmul2(x, h2rcp(__hadd2(e, one)));
}
__device__ __forceinline__ unsigned fkey(float x) {
    unsigned u = __float_as_uint(x);
    return (u & 0x80000000u) ? ~u : (u | 0x80000000u);
}
__device__ __forceinline__ float funkey(unsigned k) {
    return (k & 0x80000000u) ? __uint_as_float(k ^ 0x80000000u) : __uint_as_float(~k);
}

// ---------------------------------------------------------------------------
// Swapped-operand MFMA layer over a 64-point tile: D[ch][pt] = W * A^T.
//   A: [64][ACOLS] f16 activations, [pt][ch]; Wg: global f16 [DOUT][DIN]
// Wave w owns channel slice [w*DOUT/4, (w+1)*DOUT/4), all 4 point tiles.
// d[nt][mt]: reg r -> ch=(w*TN+mt)*16+g*4+r, pt=nt*16+i15.
// MODE 0: +bias,LN,GELU(packed f16) -> A.  MODE 1: +bias,LN(f32), max -> atomic.
// MODE 2: +bias,GELU(packed) -> A (no LN).
// ---------------------------------------------------------------------------
template<int ACOLS, int DIN, int DOUT, int MODE>
__device__ __forceinline__ void mfma_layerT(
    f16 (*A)[ACOLS],
    const f16* __restrict__ Wg, const float* __restrict__ Bias,
    const float* __restrict__ Gam, const float* __restrict__ Bet,
    float2 (*Pp)[4], unsigned* __restrict__ mk)
{
    constexpr int KS = DIN / 32, TN = DOUT / 64;
    const int tid = threadIdx.x;
    const int w = tid >> 6, lane = tid & 63;
    const int i15 = lane & 15, g = lane >> 4;

    f32x4 d[4][TN];
#pragma unroll
    for (int nt = 0; nt < 4; ++nt)
#pragma unroll
        for (int mt = 0; mt < TN; ++mt) d[nt][mt] = (f32x4){0.f, 0.f, 0.f, 0.f};

#pragma unroll 2
    for (int ks = 0; ks < KS; ++ks) {
        f16x8 wf[TN];
#pragma unroll
        for (int mt = 0; mt < TN; ++mt)
            wf[mt] = *(const f16x8*)&Wg[(size_t)((w * TN + mt) * 16 + i15) * DIN + ks * 32 + g * 8];
#pragma unroll
        for (int nt = 0; nt < 4; ++nt) {
            f16x8 af = *(const f16x8*)&A[nt * 16 + i15][ks * 32 + g * 8];
#pragma unroll
            for (int mt = 0; mt < TN; ++mt)
                d[nt][mt] = __builtin_amdgcn_mfma_f32_16x16x32_f16(wf[mt], af, d[nt][mt], 0, 0, 0);
        }
    }

    { // bias add (f32)
        float bi[TN][4];
#pragma unroll
        for (int mt = 0; mt < TN; ++mt)
            *(float4*)bi[mt] = *(const float4*)&Bias[(w * TN + mt) * 16 + g * 4];
#pragma unroll
        for (int nt = 0; nt < 4; ++nt)
#pragma unroll
            for (int mt = 0; mt < TN; ++mt)
#pragma unroll
                for (int r = 0; r < 4; ++r) d[nt][mt][r] += bi[mt][r];
    }

    if constexpr (MODE <= 1) {
        // per-point LN partials: in-lane over (mt,r) + 2 shuffles over g
#pragma unroll
        for (int nt = 0; nt < 4; ++nt) {
            float ss = 0.f, qq = 0.f;
#pragma unroll
            for (int mt = 0; mt < TN; ++mt)
#pragma unroll
                for (int r = 0; r < 4; ++r) {
                    float v = d[nt][mt][r];
                    ss += v; qq += v * v;
                }
            ss += __shfl_xor(ss, 16); qq += __shfl_xor(qq, 16);
            ss += __shfl_xor(ss, 32); qq += __shfl_xor(qq, 32);
            if (g == 0) Pp[nt * 16 + i15][w] = make_float2(ss, qq);
        }
        __syncthreads();  // Pp ready; also all ks-loop A reads done

        if constexpr (MODE == 0) {
            // ---- packed-f16 LN apply + GELU + store --------------------
            __half2 gh[TN][2], beh[TN][2];
#pragma unroll
            for (int mt = 0; mt < TN; ++mt) {
                int cb = (w * TN + mt) * 16 + g * 4;
                float4 gv = *(const float4*)&Gam[cb];
                float4 bv = *(const float4*)&Bet[cb];
                gh[mt][0] = __floats2half2_rn(gv.x, gv.y);
                gh[mt][1] = __floats2half2_rn(gv.z, gv.w);
                beh[mt][0] = __floats2half2_rn(bv.x, bv.y);
                beh[mt][1] = __floats2half2_rn(bv.z, bv.w);
            }
#pragma unroll
            for (int nt = 0; nt < 4; ++nt) {
                int pt = nt * 16 + i15;
                float4 pa = *(const float4*)&Pp[pt][0];
                float4 pb = *(const float4*)&Pp[pt][2];
                float S = pa.x + pa.z + pb.x + pb.z;
                float Q = pa.y + pa.w + pb.y + pb.w;
                float mean = S * (1.f / DOUT);
                float var = Q * (1.f / DOUT) - mean * mean;
                float rstd = rsqrtf(var + 1e-5f);
                __half2 r2 = __float2half2_rn(rstd);
                __half2 nm2 = __float2half2_rn(-mean);
#pragma unroll
                for (int mt = 0; mt < TN; ++mt) {
                    union { f16x4 v; __half2 h[2]; } u;
#pragma unroll
                    for (int j = 0; j < 2; ++j) {
                        __half2 xb = __floats2half2_rn(d[nt][mt][2 * j], d[nt][mt][2 * j + 1]);
                        __half2 k1 = __hmul2(r2, gh[mt][j]);
                        __half2 k2 = __hfma2(nm2, k1, beh[mt][j]);
                        u.h[j] = gelu_pk(__hfma2(xb, k1, k2));
                    }
                    *(f16x4*)&A[pt][(w * TN + mt) * 16 + g * 4] = u.v;
                }
            }
            __syncthreads();  // layer output visible
        } else {
            // ---- f32 LN apply + channel max + atomic (final layer) -----
            float ga[TN][4], be[TN][4];
#pragma unroll
            for (int mt = 0; mt < TN; ++mt) {
                int cb = (w * TN + mt) * 16 + g * 4;
                *(float4*)ga[mt] = *(const float4*)&Gam[cb];
                *(float4*)be[mt] = *(const float4*)&Bet[cb];
            }
            float mx[TN][4];
#pragma unroll
            for (int mt = 0; mt < TN; ++mt)
#pragma unroll
                for (int r = 0; r < 4; ++r) mx[mt][r] = -1e30f;
#pragma unroll
            for (int nt = 0; nt < 4; ++nt) {
                int pt = nt * 16 + i15;
                float4 pa = *(const float4*)&Pp[pt][0];
                float4 pb = *(const float4*)&Pp[pt][2];
                float S = pa.x + pa.z + pb.x + pb.z;
                float Q = pa.y + pa.w + pb.y + pb.w;
                float mean = S * (1.f / DOUT);
                float var = Q * (1.f / DOUT) - mean * mean;
                float rstd = rsqrtf(var + 1e-5f);
#pragma unroll
                for (int mt = 0; mt < TN; ++mt)
#pragma unroll
                    for (int r = 0; r < 4; ++r) {
                        float y = (d[nt][mt][r] - mean) * rstd * ga[mt][r] + be[mt][r];
                        mx[mt][r] = fmaxf(mx[mt][r], y);
                    }
            }
#pragma unroll
            for (int mt = 0; mt < TN; ++mt)
#pragma unroll
                for (int r = 0; r < 4; ++r) {
                    float m = mx[mt][r];
                    m = fmaxf(m, __shfl_xor(m, 1));
                    m = fmaxf(m, __shfl_xor(m, 2));
                    m = fmaxf(m, __shfl_xor(m, 4));
                    m = fmaxf(m, __shfl_xor(m, 8));
                    mx[mt][r] = m;
                }
            if (i15 == 0) {
#pragma unroll
                for (int mt = 0; mt < TN; ++mt)
#pragma unroll
                    for (int r = 0; r < 4; ++r)
                        atomicMax(&mk[(w * TN + mt) * 16 + g * 4 + r], fkey(mx[mt][r]));
            }
        }
    } else {
        __syncthreads();  // all waves done reading A
#pragma unroll
        for (int nt = 0; nt < 4; ++nt) {
            int pt = nt * 16 + i15;
#pragma unroll
            for (int mt = 0; mt < TN; ++mt) {
                union { f16x4 v; __half2 h[2]; } u;
                u.h[0] = gelu_pk(__floats2half2_rn(d[nt][mt][0], d[nt][mt][1]));
                u.h[1] = gelu_pk(__floats2half2_rn(d[nt][mt][2], d[nt][mt][3]));
                *(f16x4*)&A[pt][(w * TN + mt) * 16 + g * 4] = u.v;
            }
        }
        __syncthreads();
    }
}

// ---------------- kernel 0: init atomic-max keys ----------------------------
__global__ void init_kernel(unsigned* __restrict__ maxkey) {
    maxkey[blockIdx.x * 256 + threadIdx.x] = 0u;
}

// ---------------- kernel 0b: fp32 -> f16 weight conversion (+L1 K-pad) ------
__global__ void prep_kernel(const float* __restrict__ W1, const float* __restrict__ W2,
                            const float* __restrict__ W3, const float* __restrict__ W4,
                            f16* __restrict__ W1f, f16* __restrict__ W2f,
                            f16* __restrict__ W3f, f16* __restrict__ W4f) {
    int i = blockIdx.x * 256 + threadIdx.x;
    if (i < 128 * 32) {
        int r = i >> 5, c = i & 31;
        W1f[i] = (f16)(c < 3 ? W1[r * 3 + c] : 0.f);
    }
    int j = i - 128 * 32;
    if (j >= 0 && j < 128 * 128) W2f[j] = (f16)W2[j];
    int k = i - (128 * 32 + 128 * 128);
    if (k >= 0 && k < 256 * 128) W3f[k] = (f16)W3[k];
    int l = i - (128 * 32 + 128 * 128 + 256 * 128);
    if (l >= 0 && l < 256 * 256) W4f[l] = (f16)W4[l];
}

// ---------------- kernel 1: PointNet encoder (MFMA, swapped) ----------------
__global__ __launch_bounds__(256, 4)
void pointnet_kernel(const float* __restrict__ points,
                     const f16* __restrict__ W1f, const float* __restrict__ B1,
                     const float* __restrict__ G1, const float* __restrict__ E1,
                     const f16* __restrict__ W2f, const float* __restrict__ B2,
                     const float* __restrict__ G2, const float* __restrict__ E2,
                     const f16* __restrict__ W3f, const float* __restrict__ B3,
                     const float* __restrict__ G3, const float* __restrict__ E3,
                     const f16* __restrict__ W4f, const float* __restrict__ B4,
                     const float* __restrict__ G4, const float* __restrict__ E4,
                     unsigned* __restrict__ maxkey) {
    __shared__ __attribute__((aligned(16))) f16 A[PTILE][264];
    __shared__ float2 Pp[PTILE][4];
    const int b = blockIdx.x / PN_BLOCKS;
    const int n0 = (blockIdx.x % PN_BLOCKS) * PTILE;
    const int tid = threadIdx.x;
    // race-free staging: each 16B segment has exactly one writer
    if (tid < PTILE) {
        const float* ps = &points[((size_t)b * N_PTS + n0 + tid) * 3];
        f16x8 v = {};
        v[0] = (f16)ps[0]; v[1] = (f16)ps[1]; v[2] = (f16)ps[2];
        *(f16x8*)&A[tid][0] = v;
    } else {
        int idx = tid - PTILE, r = idx / 3, sg = idx % 3 + 1;
        f16x8 z = {};
        *(f16x8*)&A[r][sg * 8] = z;
    }
    __syncthreads();
    mfma_layerT<264, 32, 128, 0>(A, W1f, B1, G1, E1, Pp, nullptr);
    mfma_layerT<264, 128, 128, 0>(A, W2f, B2, G2, E2, Pp, nullptr);
    mfma_layerT<264, 128, 256, 0>(A, W3f, B3, G3, E3, Pp, nullptr);
    mfma_layerT<264, 256, 256, 1>(A, W4f, B4, G4, E4, Pp, maxkey + b * 256);
}

// ---------------- kernel 2: ctx + time-embed + hypernet context -------------
__global__ __launch_bounds__(256)
void hyper_kernel(const unsigned* __restrict__ maxkey, const float* __restrict__ tt,
                  const float* __restrict__ HW1, const float* __restrict__ HB1,
                  const float* __restrict__ HG1, const float* __restrict__ HE1,
                  const float* __restrict__ HW2, const float* __restrict__ HB2,
                  const float* __restrict__ HG2, const float* __restrict__ HE2,
                  float* __restrict__ c_out) {
    __shared__ float xc[320];
    __shared__ float buf[256];
    __shared__ float rs[4], rq[4];
    const int b = blockIdx.x, tid = threadIdx.x;
    xc[tid] = funkey(maxkey[b * 256 + tid]);
    if (tid < 32) {
        float emb = expf((float)tid * (-logf(10000.f) / 31.f));
        float arg = tt[b] * emb;
        xc[256 + tid] = sinf(arg);
        xc[288 + tid] = cosf(arg);
    }
    __syncthreads();
    float acc = HB1[tid];
    for (int i = 0; i < 320; i += 4) {
        float4 w = *(const float4*)&HW1[(size_t)tid * 320 + i];
        acc += xc[i] * w.x + xc[i + 1] * w.y + xc[i + 2] * w.z + xc[i + 3] * w.w;
    }
    float s = acc, q = acc * acc;
#pragma unroll
    for (int off = 32; off; off >>= 1) { s += __shfl_xor(s, off); q += __shfl_xor(q, off); }
    if ((tid & 63) == 0) { rs[tid >> 6] = s; rq[tid >> 6] = q; }
    __syncthreads();
    s = rs[0] + rs[1] + rs[2] + rs[3];
    q = rq[0] + rq[1] + rq[2] + rq[3];
    float mean = s * (1.f / 256), var = q * (1.f / 256) - mean * mean;
    float rstd = rsqrtf(var + 1e-5f);
    float h = gelu_exact((acc - mean) * rstd * HG1[tid] + HE1[tid]);
    __syncthreads();
    buf[tid] = h;
    __syncthreads();
    acc = HB2[tid];
    for (int i = 0; i < 256; i += 4) {
        float4 w = *(const float4*)&HW2[(size_t)tid * 256 + i];
        acc += buf[i] * w.x + buf[i + 1] * w.y + buf[i + 2] * w.z + buf[i + 3] * w.w;
    }
    s = acc; q = acc * acc;
#pragma unroll
    for (int off = 32; off; off >>= 1) { s += __shfl_xor(s, off); q += __shfl_xor(q, off); }
    if ((tid & 63) == 0) { rs[tid >> 6] = s; rq[tid >> 6] = q; }
    __syncthreads();
    s = rs[0] + rs[1] + rs[2] + rs[3];
    q = rq[0] + rq[1] + rq[2] + rq[3];
    mean = s * (1.f / 256); var = q * (1.f / 256) - mean * mean;
    rstd = rsqrtf(var + 1e-5f);
    c_out[b * 256 + tid] = gelu_exact((acc - mean) * rstd * HG2[tid] + HE2[tid]);
}

// ---------------- kernel 3: generate field weights + biases (f16 out) -------
__device__ __forceinline__ void gen_row(float acc[32], const float (*cs)[256],
                                        const float* __restrict__ Wg,
                                        const float* __restrict__ Wgb, int f, bool valid) {
#pragma unroll
    for (int b = 0; b < 32; ++b) acc[b] = 0.f;
    if (!valid) return;
    for (int i = 0; i < 256; i += 4) {
        float4 w = *(const float4*)&Wg[(size_t)f * 256 + i];
#pragma unroll
        for (int b = 0; b < 32; ++b) {
            float4 cv = *(const float4*)&cs[b][i];
            acc[b] += cv.x * w.x + cv.y * w.y + cv.z * w.z + cv.w * w.w;
        }
    }
    float bias = Wgb[f];
#pragma unroll
    for (int b = 0; b < 32; ++b) acc[b] += bias;
}

__global__ __launch_bounds__(256)
void wgen_kernel(const float* __restrict__ c,
                 const float* __restrict__ WG0, const float* __restrict__ WGB0,
                 const float* __restrict__ BG0, const float* __restrict__ BGB0,
                 const float* __restrict__ WG1, const float* __restrict__ WGB1,
                 const float* __restrict__ BG1, const float* __restrict__ BGB1,
                 const float* __restrict__ WG2, const float* __restrict__ WGB2,
                 const float* __restrict__ BG2, const float* __restrict__ BGB2,
                 f16* __restrict__ w0f, f16* __restrict__ w1f, f16* __restrict__ w2f,
                 float* __restrict__ bb0, float* __restrict__ bb1, float* __restrict__ bb2) {
    __shared__ float cs[32][256];
    const int tid = threadIdx.x;
    for (int i = tid; i < 32 * 256; i += 256) cs[i >> 8][i & 255] = c[i];
    __syncthreads();
    const int wave = tid >> 6, lane = tid & 63;
    const int task = blockIdx.x * 4 + wave;
    if (task >= 262) return;

    float accA[32], accB[32];
    if (task < 259) {
        int layer, o;
        if (task < 128) { layer = 0; o = task; }
        else if (task < 256) { layer = 1; o = task - 128; }
        else { layer = 2; o = task - 256; }
        const int din = (layer == 0) ? 63 : 128;
        const float* Wg = (layer == 0) ? WG0 : (layer == 1) ? WG1 : WG2;
        const float* Wgb = (layer == 0) ? WGB0 : (layer == 1) ? WGB1 : WGB2;
        const int eA = lane, eB = lane + 64;
        const bool vA = eA < din, vB = eB < din;
        gen_row(accA, cs, Wg, Wgb, o * din + eA, vA);
        gen_row(accB, cs, Wg, Wgb, o * din + eB, vB);
#pragma unroll
        for (int b = 0; b < 32; ++b) {
            float xa = vA ? accA[b] : 0.f, xb = vB ? accB[b] : 0.f;
            float sq = xa * xa + xb * xb;
#pragma unroll
            for (int off = 32; off; off >>= 1) sq += __shfl_xor(sq, off);
            float rn = 1.f / fmaxf(sqrtf(sq), 1e-12f);
            if (layer == 0) { // [128][64] f16, col 63 zeroed (K padded to 64)
                w0f[((size_t)b * 128 + o) * 64 + eA] = (f16)(vA ? accA[b] * rn : 0.f);
            } else if (layer == 1) {
                w1f[((size_t)b * 128 + o) * 128 + eA] = (f16)(accA[b] * rn);
                w1f[((size_t)b * 128 + o) * 128 + eB] = (f16)(accB[b] * rn);
            } else {
                w2f[((size_t)b * 3 + o) * 128 + eA] = (f16)(accA[b] * rn);
                w2f[((size_t)b * 3 + o) * 128 + eB] = (f16)(accB[b] * rn);
            }
        }
    } else {
        const int layer = task - 259;
        const int dout = (layer == 2) ? 3 : 128;
        const float* Bg = (layer == 0) ? BG0 : (layer == 1) ? BG1 : BG2;
        const float* Bgb = (layer == 0) ? BGB0 : (layer == 1) ? BGB1 : BGB2;
        const int eA = lane, eB = lane + 64;
        gen_row(accA, cs, Bg, Bgb, eA, eA < dout);
        gen_row(accB, cs, Bg, Bgb, eB, eB < dout);
        float* dst = (layer == 0) ? bb0 : (layer == 1) ? bb1 : bb2;
#pragma unroll
        for (int b = 0; b < 32; ++b) {
            if (eA < dout) dst[b * dout + eA] = accA[b];
            if (eB < dout) dst[b * dout + eB] = accB[b];
        }
    }
}

// ---------------- kernel 4: Fourier PE + generated field MLP (MFMA) ---------
__global__ __launch_bounds__(256, 5)
void field_kernel(const float* __restrict__ points,
                  const f16* __restrict__ w0f, const float* __restrict__ bb0,
                  const f16* __restrict__ w1f, const float* __restrict__ bb1,
                  const f16* __restrict__ w2f, const float* __restrict__ bb2,
                  float* __restrict__ out) {
    __shared__ __attribute__((aligned(16))) f16 A[PTILE][136];
    const int b = blockIdx.x / PN_BLOCKS;
    const int n0 = (blockIdx.x % PN_BLOCKS) * PTILE;
    const int tid = threadIdx.x;
    {   // thread t: point p = t>>2, column quarter q = t&3 (16 cols each)
        const int p = tid >> 2, q = tid & 3;
        float xyz[3];
#pragma unroll
        for (int dd = 0; dd < 3; ++dd)
            xyz[dd] = points[((size_t)b * N_PTS + n0 + p) * 3 + dd];
#pragma unroll
        for (int j = 0; j < 16; ++j) {
            int c = q * 16 + j;
            float val;
            if (c < 3) val = xyz[c];
            else if (c < 33) {
                int k = c - 3, dd = k / 10, f = k % 10;
                val = __sinf(xyz[dd] * ((float)(1 << f) * 3.14159265358979f));
            } else if (c < 63) {
                int k = c - 33, dd = k / 10, f = k % 10;
                val = __cosf(xyz[dd] * ((float)(1 << f) * 3.14159265358979f));
            } else val = 0.f;
            A[p][c] = (f16)val;
        }
    }
    __syncthreads();
    mfma_layerT<136, 64, 128, 2>(A, w0f + (size_t)b * 128 * 64, bb0 + b * 128,
                                 nullptr, nullptr, nullptr, nullptr);
    mfma_layerT<136, 128, 128, 2>(A, w1f + (size_t)b * 128 * 128, bb1 + b * 128,
                                  nullptr, nullptr, nullptr, nullptr);
    // final 128 -> 3 (tiny; fp32 dot on f16 activations)
    if (tid < PTILE * 3) {
        int p = tid / 3, ch = tid % 3;
        const f16* wr = w2f + ((size_t)b * 3 + ch) * 128;
        float acc = 0.f;
        for (int k = 0; k < 128; k += 8) {
            f16x8 av = *(const f16x8*)&A[p][k];
            f16x8 wv = *(const f16x8*)&wr[k];
#pragma unroll
            for (int j = 0; j < 8; ++j) acc += (float)av[j] * (float)wv[j];
        }
        out[((size_t)b * N_PTS + n0 + p) * 3 + ch] = acc + bb2[b * 3 + ch];
    }
}

extern "C" void kernel_launch(void* const* d_in, const int* in_sizes, int n_in,
                              void* d_out, int out_size, void* d_ws, size_t ws_size,
                              hipStream_t stream) {
    const float* points = (const float*)d_in[0];
    const float* tt = (const float*)d_in[1];
    const float* pw1 = (const float*)d_in[2],  *pb1 = (const float*)d_in[3];
    const float* pg1 = (const float*)d_in[4],  *pe1 = (const float*)d_in[5];
    const float* pw2 = (const float*)d_in[6],  *pb2 = (const float*)d_in[7];
    const float* pg2 = (const float*)d_in[8],  *pe2 = (const float*)d_in[9];
    const float* pw3 = (const float*)d_in[10], *pb3 = (const float*)d_in[11];
    const float* pg3 = (const float*)d_in[12], *pe3 = (const float*)d_in[13];
    const float* pw4 = (const float*)d_in[14], *pb4 = (const float*)d_in[15];
    const float* pg4 = (const float*)d_in[16], *pe4 = (const float*)d_in[17];
    const float* hw1 = (const float*)d_in[18], *hb1 = (const float*)d_in[19];
    const float* hg1 = (const float*)d_in[20], *he1 = (const float*)d_in[21];
    const float* hw2 = (const float*)d_in[22], *hb2 = (const float*)d_in[23];
    const float* hg2 = (const float*)d_in[24], *he2 = (const float*)d_in[25];
    const float* wg0w = (const float*)d_in[26], *wg0b = (const float*)d_in[27];
    const float* bg0w = (const float*)d_in[28], *bg0b = (const float*)d_in[29];
    const float* wg1w = (const float*)d_in[30], *wg1b = (const float*)d_in[31];
    const float* bg1w = (const float*)d_in[32], *bg1b = (const float*)d_in[33];
    const float* wg2w = (const float*)d_in[34], *wg2b = (const float*)d_in[35];
    const float* bg2w = (const float*)d_in[36], *bg2b = (const float*)d_in[37];

    // ---- workspace layout ----
    char* p = (char*)d_ws;
    unsigned* maxkey = (unsigned*)p;           p += 8192 * 4;     // [32][256]
    float* c_buf = (float*)p;                  p += 8192 * 4;     // [32][256]
    float* bb0 = (float*)p;                    p += 4096 * 4;
    float* bb1 = (float*)p;                    p += 4096 * 4;
    float* bb2 = (float*)p;                    p += 96 * 4 + 64;
    f16* W1f = (f16*)p;                        p += 128 * 32 * 2;
    f16* W2f = (f16*)p;                        p += 128 * 128 * 2;
    f16* W3f = (f16*)p;                        p += 256 * 128 * 2;
    f16* W4f = (f16*)p;                        p += 256 * 256 * 2;
    f16* w0f = (f16*)p;                        p += (size_t)32 * 128 * 64 * 2;
    f16* w1f = (f16*)p;                        p += (size_t)32 * 128 * 128 * 2;
    f16* w2f = (f16*)p;                        p += (size_t)32 * 3 * 128 * 2;

    init_kernel<<<32, 256, 0, stream>>>(maxkey);
    prep_kernel<<<464, 256, 0, stream>>>(pw1, pw2, pw3, pw4, W1f, W2f, W3f, W4f);
    pointnet_kernel<<<NBATCH * PN_BLOCKS, 256, 0, stream>>>(
        points, W1f, pb1, pg1, pe1, W2f, pb2, pg2, pe2,
        W3f, pb3, pg3, pe3, W4f, pb4, pg4, pe4, maxkey);
    hyper_kernel<<<NBATCH, 256, 0, stream>>>(
        maxkey, tt, hw1, hb1, hg1, he1, hw2, hb2, hg2, he2, c_buf);
    wgen_kernel<<<66, 256, 0, stream>>>(
        c_buf, wg0w, wg0b, bg0w, bg0b, wg1w, wg1b, bg1w, bg1b,
        wg2w, wg2b, bg2w, bg2b, w0f, w1f, w2f, bb0, bb1, bb2);
    field_kernel<<<NBATCH * PN_BLOCKS, 256, 0, stream>>>(
        points, w0f, bb0, w1f, bb1, w2f, bb2, (float*)d_out);
}

// Round 9
// 737.260 us; speedup vs baseline: 4.6000x; 1.0516x over previous
//
#include <hip/hip_runtime.h>
#include <hip/hip_fp16.h>

typedef _Float16 f16;
typedef f16 f16x8 __attribute__((ext_vector_type(8)));
typedef f16 f16x4 __attribute__((ext_vector_type(4)));
typedef float f32x4 __attribute__((ext_vector_type(4)));

#define N_PTS 16384
#define NBATCH 32
#define PTILE 64
#define PN_BLOCKS (N_PTS / PTILE) /* 256 */

__device__ __forceinline__ float gelu_exact(float x) {
    return 0.5f * x * (1.0f + erff(x * 0.70710678118654752440f));
}
// packed tanh-GELU: x*sigmoid(1.5958x+0.07135x^3), exp2-folded, in half2
__device__ __forceinline__ __half2 gelu_pk(__half2 x) {
    const __half2 c1 = __float2half2_rn(-0.10293984f);   // -log2(e)*0.07135481627
    const __half2 c2 = __float2half2_rn(-2.30220830f);   // -log2(e)*1.59576912
    const __half2 one = __float2half2_rn(1.0f);
    __half2 u = __hmul2(x, x);
    __half2 t = __hmul2(x, __hfma2(u, c1, c2));
    __half2 e = h2exp2(t);                               // x<<0: e->inf -> y=0; x>>0: e->0 -> y=x
    return __hmul2(x, h2rcp(__hadd2(e, one)));
}
__device__ __forceinline__ unsigned fkey(float x) {
    unsigned u = __float_as_uint(x);
    return (u & 0x80000000u) ? ~u : (u | 0x80000000u);
}
__device__ __forceinline__ float funkey(unsigned k) {
    return (k & 0x80000000u) ? __uint_as_float(k ^ 0x80000000u) : __uint_as_float(~k);
}

// ---------------------------------------------------------------------------
// Swapped-operand MFMA layer over a 64-point tile: D[ch][pt] = W * A^T.
//   A: [64][ACOLS] f16 activations, [pt][ch]; Wg: global f16 [DOUT][DIN]
// Wave w owns channel slice [w*DOUT/4, (w+1)*DOUT/4), all 4 point tiles.
// d[nt][mt]: reg r -> ch=(w*TN+mt)*16+g*4+r, pt=nt*16+i15.
// MODE 0: +bias,LN,GELU(packed f16) -> A.  MODE 1: +bias,LN(f32), max -> atomic.
// MODE 2: +bias,GELU(packed) -> A (no LN).
// ---------------------------------------------------------------------------
template<int ACOLS, int DIN, int DOUT, int MODE>
__device__ __forceinline__ void mfma_layerT(
    f16 (*A)[ACOLS],
    const f16* __restrict__ Wg, const float* __restrict__ Bias,
    const float* __restrict__ Gam, const float* __restrict__ Bet,
    float2 (*Pp)[4], unsigned* __restrict__ mk)
{
    constexpr int KS = DIN / 32, TN = DOUT / 64;
    const int tid = threadIdx.x;
    const int w = tid >> 6, lane = tid & 63;
    const int i15 = lane & 15, g = lane >> 4;

    f32x4 d[4][TN];
#pragma unroll
    for (int nt = 0; nt < 4; ++nt)
#pragma unroll
        for (int mt = 0; mt < TN; ++mt) d[nt][mt] = (f32x4){0.f, 0.f, 0.f, 0.f};

#pragma unroll 2
    for (int ks = 0; ks < KS; ++ks) {
        f16x8 wf[TN];
#pragma unroll
        for (int mt = 0; mt < TN; ++mt)
            wf[mt] = *(const f16x8*)&Wg[(size_t)((w * TN + mt) * 16 + i15) * DIN + ks * 32 + g * 8];
#pragma unroll
        for (int nt = 0; nt < 4; ++nt) {
            f16x8 af = *(const f16x8*)&A[nt * 16 + i15][ks * 32 + g * 8];
#pragma unroll
            for (int mt = 0; mt < TN; ++mt)
                d[nt][mt] = __builtin_amdgcn_mfma_f32_16x16x32_f16(wf[mt], af, d[nt][mt], 0, 0, 0);
        }
    }

    { // bias add (f32)
        float bi[TN][4];
#pragma unroll
        for (int mt = 0; mt < TN; ++mt)
            *(float4*)bi[mt] = *(const float4*)&Bias[(w * TN + mt) * 16 + g * 4];
#pragma unroll
        for (int nt = 0; nt < 4; ++nt)
#pragma unroll
            for (int mt = 0; mt < TN; ++mt)
#pragma unroll
                for (int r = 0; r < 4; ++r) d[nt][mt][r] += bi[mt][r];
    }

    if constexpr (MODE <= 1) {
        // per-point LN partials: in-lane over (mt,r) + 2 shuffles over g
#pragma unroll
        for (int nt = 0; nt < 4; ++nt) {
            float ss = 0.f, qq = 0.f;
#pragma unroll
            for (int mt = 0; mt < TN; ++mt)
#pragma unroll
                for (int r = 0; r < 4; ++r) {
                    float v = d[nt][mt][r];
                    ss += v; qq += v * v;
                }
            ss += __shfl_xor(ss, 16); qq += __shfl_xor(qq, 16);
            ss += __shfl_xor(ss, 32); qq += __shfl_xor(qq, 32);
            if (g == 0) Pp[nt * 16 + i15][w] = make_float2(ss, qq);
        }
        __syncthreads();  // Pp ready; also all ks-loop A reads done

        if constexpr (MODE == 0) {
            // ---- packed-f16 LN apply + GELU + store --------------------
            __half2 gh[TN][2], beh[TN][2];
#pragma unroll
            for (int mt = 0; mt < TN; ++mt) {
                int cb = (w * TN + mt) * 16 + g * 4;
                float4 gv = *(const float4*)&Gam[cb];
                float4 bv = *(const float4*)&Bet[cb];
                gh[mt][0] = __floats2half2_rn(gv.x, gv.y);
                gh[mt][1] = __floats2half2_rn(gv.z, gv.w);
                beh[mt][0] = __floats2half2_rn(bv.x, bv.y);
                beh[mt][1] = __floats2half2_rn(bv.z, bv.w);
            }
#pragma unroll
            for (int nt = 0; nt < 4; ++nt) {
                int pt = nt * 16 + i15;
                float4 pa = *(const float4*)&Pp[pt][0];
                float4 pb = *(const float4*)&Pp[pt][2];
                float S = pa.x + pa.z + pb.x + pb.z;
                float Q = pa.y + pa.w + pb.y + pb.w;
                float mean = S * (1.f / DOUT);
                float var = Q * (1.f / DOUT) - mean * mean;
                float rstd = rsqrtf(var + 1e-5f);
                __half2 r2 = __float2half2_rn(rstd);
                __half2 nm2 = __float2half2_rn(-mean);
#pragma unroll
                for (int mt = 0; mt < TN; ++mt) {
                    union { f16x4 v; __half2 h[2]; } u;
#pragma unroll
                    for (int j = 0; j < 2; ++j) {
                        __half2 xb = __floats2half2_rn(d[nt][mt][2 * j], d[nt][mt][2 * j + 1]);
                        __half2 k1 = __hmul2(r2, gh[mt][j]);
                        __half2 k2 = __hfma2(nm2, k1, beh[mt][j]);
                        u.h[j] = gelu_pk(__hfma2(xb, k1, k2));
                    }
                    *(f16x4*)&A[pt][(w * TN + mt) * 16 + g * 4] = u.v;
                }
            }
            __syncthreads();  // layer output visible
        } else {
            // ---- f32 LN apply + channel max + atomic (final layer) -----
            float ga[TN][4], be[TN][4];
#pragma unroll
            for (int mt = 0; mt < TN; ++mt) {
                int cb = (w * TN + mt) * 16 + g * 4;
                *(float4*)ga[mt] = *(const float4*)&Gam[cb];
                *(float4*)be[mt] = *(const float4*)&Bet[cb];
            }
            float mx[TN][4];
#pragma unroll
            for (int mt = 0; mt < TN; ++mt)
#pragma unroll
                for (int r = 0; r < 4; ++r) mx[mt][r] = -1e30f;
#pragma unroll
            for (int nt = 0; nt < 4; ++nt) {
                int pt = nt * 16 + i15;
                float4 pa = *(const float4*)&Pp[pt][0];
                float4 pb = *(const float4*)&Pp[pt][2];
                float S = pa.x + pa.z + pb.x + pb.z;
                float Q = pa.y + pa.w + pb.y + pb.w;
                float mean = S * (1.f / DOUT);
                float var = Q * (1.f / DOUT) - mean * mean;
                float rstd = rsqrtf(var + 1e-5f);
#pragma unroll
                for (int mt = 0; mt < TN; ++mt)
#pragma unroll
                    for (int r = 0; r < 4; ++r) {
                        float y = (d[nt][mt][r] - mean) * rstd * ga[mt][r] + be[mt][r];
                        mx[mt][r] = fmaxf(mx[mt][r], y);
                    }
            }
#pragma unroll
            for (int mt = 0; mt < TN; ++mt)
#pragma unroll
                for (int r = 0; r < 4; ++r) {
                    float m = mx[mt][r];
                    m = fmaxf(m, __shfl_xor(m, 1));
                    m = fmaxf(m, __shfl_xor(m, 2));
                    m = fmaxf(m, __shfl_xor(m, 4));
                    m = fmaxf(m, __shfl_xor(m, 8));
                    mx[mt][r] = m;
                }
            if (i15 == 0) {
#pragma unroll
                for (int mt = 0; mt < TN; ++mt)
#pragma unroll
                    for (int r = 0; r < 4; ++r)
                        atomicMax(&mk[(w * TN + mt) * 16 + g * 4 + r], fkey(mx[mt][r]));
            }
        }
    } else {
        __syncthreads();  // all waves done reading A
#pragma unroll
        for (int nt = 0; nt < 4; ++nt) {
            int pt = nt * 16 + i15;
#pragma unroll
            for (int mt = 0; mt < TN; ++mt) {
                union { f16x4 v; __half2 h[2]; } u;
                u.h[0] = gelu_pk(__floats2half2_rn(d[nt][mt][0], d[nt][mt][1]));
                u.h[1] = gelu_pk(__floats2half2_rn(d[nt][mt][2], d[nt][mt][3]));
                *(f16x4*)&A[pt][(w * TN + mt) * 16 + g * 4] = u.v;
            }
        }
        __syncthreads();
    }
}

// ---------------- kernel 0: init atomic-max keys ----------------------------
__global__ void init_kernel(unsigned* __restrict__ maxkey) {
    maxkey[blockIdx.x * 256 + threadIdx.x] = 0u;
}

// ---------------- kernel 0b: fp32 -> f16 weight conversion (+L1 K-pad) ------
__global__ void prep_kernel(const float* __restrict__ W1, const float* __restrict__ W2,
                            const float* __restrict__ W3, const float* __restrict__ W4,
                            f16* __restrict__ W1f, f16* __restrict__ W2f,
                            f16* __restrict__ W3f, f16* __restrict__ W4f) {
    int i = blockIdx.x * 256 + threadIdx.x;
    if (i < 128 * 32) {
        int r = i >> 5, c = i & 31;
        W1f[i] = (f16)(c < 3 ? W1[r * 3 + c] : 0.f);
    }
    int j = i - 128 * 32;
    if (j >= 0 && j < 128 * 128) W2f[j] = (f16)W2[j];
    int k = i - (128 * 32 + 128 * 128);
    if (k >= 0 && k < 256 * 128) W3f[k] = (f16)W3[k];
    int l = i - (128 * 32 + 128 * 128 + 256 * 128);
    if (l >= 0 && l < 256 * 256) W4f[l] = (f16)W4[l];
}

// ---------------- kernel 1: PointNet encoder (MFMA, swapped) ----------------
__global__ __launch_bounds__(256, 3)
void pointnet_kernel(const float* __restrict__ points,
                     const f16* __restrict__ W1f, const float* __restrict__ B1,
                     const float* __restrict__ G1, const float* __restrict__ E1,
                     const f16* __restrict__ W2f, const float* __restrict__ B2,
                     const float* __restrict__ G2, const float* __restrict__ E2,
                     const f16* __restrict__ W3f, const float* __restrict__ B3,
                     const float* __restrict__ G3, const float* __restrict__ E3,
                     const f16* __restrict__ W4f, const float* __restrict__ B4,
                     const float* __restrict__ G4, const float* __restrict__ E4,
                     unsigned* __restrict__ maxkey) {
    __shared__ __attribute__((aligned(16))) f16 A[PTILE][264];
    __shared__ float2 Pp[PTILE][4];
    const int b = blockIdx.x / PN_BLOCKS;
    const int n0 = (blockIdx.x % PN_BLOCKS) * PTILE;
    const int tid = threadIdx.x;
    // race-free staging: each 16B segment has exactly one writer
    if (tid < PTILE) {
        const float* ps = &points[((size_t)b * N_PTS + n0 + tid) * 3];
        f16x8 v = {};
        v[0] = (f16)ps[0]; v[1] = (f16)ps[1]; v[2] = (f16)ps[2];
        *(f16x8*)&A[tid][0] = v;
    } else {
        int idx = tid - PTILE, r = idx / 3, sg = idx % 3 + 1;
        f16x8 z = {};
        *(f16x8*)&A[r][sg * 8] = z;
    }
    __syncthreads();
    mfma_layerT<264, 32, 128, 0>(A, W1f, B1, G1, E1, Pp, nullptr);
    mfma_layerT<264, 128, 128, 0>(A, W2f, B2, G2, E2, Pp, nullptr);
    mfma_layerT<264, 128, 256, 0>(A, W3f, B3, G3, E3, Pp, nullptr);
    mfma_layerT<264, 256, 256, 1>(A, W4f, B4, G4, E4, Pp, maxkey + b * 256);
}

// ---------------- kernel 2: ctx + time-embed + hypernet context -------------
__global__ __launch_bounds__(256)
void hyper_kernel(const unsigned* __restrict__ maxkey, const float* __restrict__ tt,
                  const float* __restrict__ HW1, const float* __restrict__ HB1,
                  const float* __restrict__ HG1, const float* __restrict__ HE1,
                  const float* __restrict__ HW2, const float* __restrict__ HB2,
                  const float* __restrict__ HG2, const float* __restrict__ HE2,
                  float* __restrict__ c_out) {
    __shared__ float xc[320];
    __shared__ float buf[256];
    __shared__ float rs[4], rq[4];
    const int b = blockIdx.x, tid = threadIdx.x;
    xc[tid] = funkey(maxkey[b * 256 + tid]);
    if (tid < 32) {
        float emb = expf((float)tid * (-logf(10000.f) / 31.f));
        float arg = tt[b] * emb;
        xc[256 + tid] = sinf(arg);
        xc[288 + tid] = cosf(arg);
    }
    __syncthreads();
    float acc = HB1[tid];
    for (int i = 0; i < 320; i += 4) {
        float4 w = *(const float4*)&HW1[(size_t)tid * 320 + i];
        acc += xc[i] * w.x + xc[i + 1] * w.y + xc[i + 2] * w.z + xc[i + 3] * w.w;
    }
    float s = acc, q = acc * acc;
#pragma unroll
    for (int off = 32; off; off >>= 1) { s += __shfl_xor(s, off); q += __shfl_xor(q, off); }
    if ((tid & 63) == 0) { rs[tid >> 6] = s; rq[tid >> 6] = q; }
    __syncthreads();
    s = rs[0] + rs[1] + rs[2] + rs[3];
    q = rq[0] + rq[1] + rq[2] + rq[3];
    float mean = s * (1.f / 256), var = q * (1.f / 256) - mean * mean;
    float rstd = rsqrtf(var + 1e-5f);
    float h = gelu_exact((acc - mean) * rstd * HG1[tid] + HE1[tid]);
    __syncthreads();
    buf[tid] = h;
    __syncthreads();
    acc = HB2[tid];
    for (int i = 0; i < 256; i += 4) {
        float4 w = *(const float4*)&HW2[(size_t)tid * 256 + i];
        acc += buf[i] * w.x + buf[i + 1] * w.y + buf[i + 2] * w.z + buf[i + 3] * w.w;
    }
    s = acc; q = acc * acc;
#pragma unroll
    for (int off = 32; off; off >>= 1) { s += __shfl_xor(s, off); q += __shfl_xor(q, off); }
    if ((tid & 63) == 0) { rs[tid >> 6] = s; rq[tid >> 6] = q; }
    __syncthreads();
    s = rs[0] + rs[1] + rs[2] + rs[3];
    q = rq[0] + rq[1] + rq[2] + rq[3];
    mean = s * (1.f / 256); var = q * (1.f / 256) - mean * mean;
    rstd = rsqrtf(var + 1e-5f);
    c_out[b * 256 + tid] = gelu_exact((acc - mean) * rstd * HG2[tid] + HE2[tid]);
}

// ---------------- kernel 3: generate field weights + biases (f16 out) -------
__device__ __forceinline__ void gen_row(float acc[32], const float (*cs)[256],
                                        const float* __restrict__ Wg,
                                        const float* __restrict__ Wgb, int f, bool valid) {
#pragma unroll
    for (int b = 0; b < 32; ++b) acc[b] = 0.f;
    if (!valid) return;
    for (int i = 0; i < 256; i += 4) {
        float4 w = *(const float4*)&Wg[(size_t)f * 256 + i];
#pragma unroll
        for (int b = 0; b < 32; ++b) {
            float4 cv = *(const float4*)&cs[b][i];
            acc[b] += cv.x * w.x + cv.y * w.y + cv.z * w.z + cv.w * w.w;
        }
    }
    float bias = Wgb[f];
#pragma unroll
    for (int b = 0; b < 32; ++b) acc[b] += bias;
}

__global__ __launch_bounds__(256)
void wgen_kernel(const float* __restrict__ c,
                 const float* __restrict__ WG0, const float* __restrict__ WGB0,
                 const float* __restrict__ BG0, const float* __restrict__ BGB0,
                 const float* __restrict__ WG1, const float* __restrict__ WGB1,
                 const float* __restrict__ BG1, const float* __restrict__ BGB1,
                 const float* __restrict__ WG2, const float* __restrict__ WGB2,
                 const float* __restrict__ BG2, const float* __restrict__ BGB2,
                 f16* __restrict__ w0f, f16* __restrict__ w1f, f16* __restrict__ w2f,
                 float* __restrict__ bb0, float* __restrict__ bb1, float* __restrict__ bb2) {
    __shared__ float cs[32][256];
    const int tid = threadIdx.x;
    for (int i = tid; i < 32 * 256; i += 256) cs[i >> 8][i & 255] = c[i];
    __syncthreads();
    const int wave = tid >> 6, lane = tid & 63;
    const int task = blockIdx.x * 4 + wave;
    if (task >= 262) return;

    float accA[32], accB[32];
    if (task < 259) {
        int layer, o;
        if (task < 128) { layer = 0; o = task; }
        else if (task < 256) { layer = 1; o = task - 128; }
        else { layer = 2; o = task - 256; }
        const int din = (layer == 0) ? 63 : 128;
        const float* Wg = (layer == 0) ? WG0 : (layer == 1) ? WG1 : WG2;
        const float* Wgb = (layer == 0) ? WGB0 : (layer == 1) ? WGB1 : WGB2;
        const int eA = lane, eB = lane + 64;
        const bool vA = eA < din, vB = eB < din;
        gen_row(accA, cs, Wg, Wgb, o * din + eA, vA);
        gen_row(accB, cs, Wg, Wgb, o * din + eB, vB);
#pragma unroll
        for (int b = 0; b < 32; ++b) {
            float xa = vA ? accA[b] : 0.f, xb = vB ? accB[b] : 0.f;
            float sq = xa * xa + xb * xb;
#pragma unroll
            for (int off = 32; off; off >>= 1) sq += __shfl_xor(sq, off);
            float rn = 1.f / fmaxf(sqrtf(sq), 1e-12f);
            if (layer == 0) { // [128][64] f16, col 63 zeroed (K padded to 64)
                w0f[((size_t)b * 128 + o) * 64 + eA] = (f16)(vA ? accA[b] * rn : 0.f);
            } else if (layer == 1) {
                w1f[((size_t)b * 128 + o) * 128 + eA] = (f16)(accA[b] * rn);
                w1f[((size_t)b * 128 + o) * 128 + eB] = (f16)(accB[b] * rn);
            } else {
                w2f[((size_t)b * 3 + o) * 128 + eA] = (f16)(accA[b] * rn);
                w2f[((size_t)b * 3 + o) * 128 + eB] = (f16)(accB[b] * rn);
            }
        }
    } else {
        const int layer = task - 259;
        const int dout = (layer == 2) ? 3 : 128;
        const float* Bg = (layer == 0) ? BG0 : (layer == 1) ? BG1 : BG2;
        const float* Bgb = (layer == 0) ? BGB0 : (layer == 1) ? BGB1 : BGB2;
        const int eA = lane, eB = lane + 64;
        gen_row(accA, cs, Bg, Bgb, eA, eA < dout);
        gen_row(accB, cs, Bg, Bgb, eB, eB < dout);
        float* dst = (layer == 0) ? bb0 : (layer == 1) ? bb1 : bb2;
#pragma unroll
        for (int b = 0; b < 32; ++b) {
            if (eA < dout) dst[b * dout + eA] = accA[b];
            if (eB < dout) dst[b * dout + eB] = accB[b];
        }
    }
}

// ---------------- kernel 4: Fourier PE + generated field MLP (MFMA) ---------
__global__ __launch_bounds__(256, 5)
void field_kernel(const float* __restrict__ points,
                  const f16* __restrict__ w0f, const float* __restrict__ bb0,
                  const f16* __restrict__ w1f, const float* __restrict__ bb1,
                  const f16* __restrict__ w2f, const float* __restrict__ bb2,
                  float* __restrict__ out) {
    __shared__ __attribute__((aligned(16))) f16 A[PTILE][136];
    const int b = blockIdx.x / PN_BLOCKS;
    const int n0 = (blockIdx.x % PN_BLOCKS) * PTILE;
    const int tid = threadIdx.x;
    {   // thread t: point p = t>>2, column quarter q = t&3 (16 cols each)
        const int p = tid >> 2, q = tid & 3;
        float xyz[3];
#pragma unroll
        for (int dd = 0; dd < 3; ++dd)
            xyz[dd] = points[((size_t)b * N_PTS + n0 + p) * 3 + dd];
#pragma unroll
        for (int j = 0; j < 16; ++j) {
            int c = q * 16 + j;
            float val;
            if (c < 3) val = xyz[c];
            else if (c < 33) {
                int k = c - 3, dd = k / 10, f = k % 10;
                val = __sinf(xyz[dd] * ((float)(1 << f) * 3.14159265358979f));
            } else if (c < 63) {
                int k = c - 33, dd = k / 10, f = k % 10;
                val = __cosf(xyz[dd] * ((float)(1 << f) * 3.14159265358979f));
            } else val = 0.f;
            A[p][c] = (f16)val;
        }
    }
    __syncthreads();
    mfma_layerT<136, 64, 128, 2>(A, w0f + (size_t)b * 128 * 64, bb0 + b * 128,
                                 nullptr, nullptr, nullptr, nullptr);
    mfma_layerT<136, 128, 128, 2>(A, w1f + (size_t)b * 128 * 128, bb1 + b * 128,
                                  nullptr, nullptr, nullptr, nullptr);
    // final 128 -> 3 (tiny; fp32 dot on f16 activations)
    if (tid < PTILE * 3) {
        int p = tid / 3, ch = tid % 3;
        const f16* wr = w2f + ((size_t)b * 3 + ch) * 128;
        float acc = 0.f;
        for (int k = 0; k < 128; k += 8) {
            f16x8 av = *(const f16x8*)&A[p][k];
            f16x8 wv = *(const f16x8*)&wr[k];
#pragma unroll
            for (int j = 0; j < 8; ++j) acc += (float)av[j] * (float)wv[j];
        }
        out[((size_t)b * N_PTS + n0 + p) * 3 + ch] = acc + bb2[b * 3 + ch];
    }
}

extern "C" void kernel_launch(void* const* d_in, const int* in_sizes, int n_in,
                              void* d_out, int out_size, void* d_ws, size_t ws_size,
                              hipStream_t stream) {
    const float* points = (const float*)d_in[0];
    const float* tt = (const float*)d_in[1];
    const float* pw1 = (const float*)d_in[2],  *pb1 = (const float*)d_in[3];
    const float* pg1 = (const float*)d_in[4],  *pe1 = (const float*)d_in[5];
    const float* pw2 = (const float*)d_in[6],  *pb2 = (const float*)d_in[7];
    const float* pg2 = (const float*)d_in[8],  *pe2 = (const float*)d_in[9];
    const float* pw3 = (const float*)d_in[10], *pb3 = (const float*)d_in[11];
    const float* pg3 = (const float*)d_in[12], *pe3 = (const float*)d_in[13];
    const float* pw4 = (const float*)d_in[14], *pb4 = (const float*)d_in[15];
    const float* pg4 = (const float*)d_in[16], *pe4 = (const float*)d_in[17];
    const float* hw1 = (const float*)d_in[18], *hb1 = (const float*)d_in[19];
    const float* hg1 = (const float*)d_in[20], *he1 = (const float*)d_in[21];
    const float* hw2 = (const float*)d_in[22], *hb2 = (const float*)d_in[23];
    const float* hg2 = (const float*)d_in[24], *he2 = (const float*)d_in[25];
    const float* wg0w = (const float*)d_in[26], *wg0b = (const float*)d_in[27];
    const float* bg0w = (const float*)d_in[28], *bg0b = (const float*)d_in[29];
    const float* wg1w = (const float*)d_in[30], *wg1b = (const float*)d_in[31];
    const float* bg1w = (const float*)d_in[32], *bg1b = (const float*)d_in[33];
    const float* wg2w = (const float*)d_in[34], *wg2b = (const float*)d_in[35];
    const float* bg2w = (const float*)d_in[36], *bg2b = (const float*)d_in[37];

    // ---- workspace layout ----
    char* p = (char*)d_ws;
    unsigned* maxkey = (unsigned*)p;           p += 8192 * 4;     // [32][256]
    float* c_buf = (float*)p;                  p += 8192 * 4;     // [32][256]
    float* bb0 = (float*)p;                    p += 4096 * 4;
    float* bb1 = (float*)p;                    p += 4096 * 4;
    float* bb2 = (float*)p;                    p += 96 * 4 + 64;
    f16* W1f = (f16*)p;                        p += 128 * 32 * 2;
    f16* W2f = (f16*)p;                        p += 128 * 128 * 2;
    f16* W3f = (f16*)p;                        p += 256 * 128 * 2;
    f16* W4f = (f16*)p;                        p += 256 * 256 * 2;
    f16* w0f = (f16*)p;                        p += (size_t)32 * 128 * 64 * 2;
    f16* w1f = (f16*)p;                        p += (size_t)32 * 128 * 128 * 2;
    f16* w2f = (f16*)p;                        p += (size_t)32 * 3 * 128 * 2;

    init_kernel<<<32, 256, 0, stream>>>(maxkey);
    prep_kernel<<<464, 256, 0, stream>>>(pw1, pw2, pw3, pw4, W1f, W2f, W3f, W4f);
    pointnet_kernel<<<NBATCH * PN_BLOCKS, 256, 0, stream>>>(
        points, W1f, pb1, pg1, pe1, W2f, pb2, pg2, pe2,
        W3f, pb3, pg3, pe3, W4f, pb4, pg4, pe4, maxkey);
    hyper_kernel<<<NBATCH, 256, 0, stream>>>(
        maxkey, tt, hw1, hb1, hg1, he1, hw2, hb2, hg2, he2, c_buf);
    wgen_kernel<<<66, 256, 0, stream>>>(
        c_buf, wg0w, wg0b, bg0w, bg0b, wg1w, wg1b, bg1w, bg1b,
        wg2w, wg2b, bg2w, bg2b, w0f, w1f, w2f, bb0, bb1, bb2);
    field_kernel<<<NBATCH * PN_BLOCKS, 256, 0, stream>>>(
        points, w0f, bb0, w1f, bb1, w2f, bb2, (float*)d_out);
}